// Round 9
// baseline (799.428 us; speedup 1.0000x reference)
//
#include <hip/hip_runtime.h>
#include <cstdio>
#include <cmath>

typedef __attribute__((ext_vector_type(8))) short bf16x8;
typedef __attribute__((ext_vector_type(4))) float f32x4;

#define MFMA16(a, b, c) __builtin_amdgcn_mfma_f32_16x16x32_bf16((a), (b), (c), 0, 0, 0)

// ---------------- workspace layout (byte offsets) ----------------
#define WSO_PE    0u                          // float[128*128]
#define WSO_PWQS  65536u                      // bf16 packed [512][256]  (Wq@qp | sp)
#define WSO_PWK   (WSO_PWQS + 262144u)        // bf16 packed [256][512]  Wk@kp
#define WSO_PWV   (WSO_PWK + 262144u)         // bf16 packed [256][256]  Wv@vp
#define WSO_WOP   (WSO_PWV + 131072u)         // bf16 [256][256] row-major (k_wattn)
#define WSO_WC    (WSO_WOP + 131072u)         // bf16 conv fragment-packed
#define WSO_TB    (WSO_WC + 2359296u)         // f32 [6][128][256] PE tables
#define WSO_QH    (WSO_TB + 786432u)          // bf16 [2048][8][64][32]
#define WSO_KH    (WSO_QH + 67108864u)        // bf16 [2048][8][64][32]
#define WSO_VT    (WSO_KH + 67108864u)        // bf16 [2048][8][32][64]
#define WSO_YT    (WSO_VT + 67108864u)        // bf16 [8][16cc][128][128][32c]
#define WSO_SUMS  (WSO_YT + 134217728u)       // float[512]
#define WSO_SC    (WSO_SUMS + 2048u)          // float[512]
#define WSO_TOTAL (WSO_SC + 2048u)

#define SMEM_CONV 152064
#define SMEM_PROJ 66048   // 128 rows x 258 shorts x 2B

__device__ __forceinline__ unsigned short f2b(float x) {
  unsigned int u = __builtin_bit_cast(unsigned int, x);
  u += 0x7fffu + ((u >> 16) & 1u);
  return (unsigned short)(u >> 16);
}

__device__ __forceinline__ bf16x8 rd8(const unsigned short* s, int row, int stride, int k) {
  return *reinterpret_cast<const bf16x8*>(s + row * stride + (k ^ ((row & 7) << 3)));
}

// fragment-pack index for MFMA A operands: [kc][moG][rt][ks][lane][8]
__device__ __forceinline__ unsigned pack_idx(unsigned oc, unsigned ch, unsigned Mdiv) {
  unsigned kc = ch >> 6, moG = oc >> 6, rt = (oc >> 4) & 3, ks = (ch >> 5) & 1;
  unsigned l = (oc & 15) | (((ch >> 3) & 3) << 4), e = ch & 7;
  return ((((kc * Mdiv + moG) * 4 + rt) * 2 + ks) * 64 + l) * 8 + e;
}

// ================= prep: pe table + weight conversions =================
__global__ void k_prep(const float* __restrict__ spw, const float* __restrict__ opw,
                       const float* __restrict__ postw,
                       float* __restrict__ peT, unsigned short* __restrict__ pwqs,
                       unsigned short* __restrict__ wop, unsigned short* __restrict__ wc) {
  unsigned id = blockIdx.x * 256u + threadIdx.x;
  if (id < 16384u) {
    int p = id >> 7, j = id & 127;
    float div = expf(-9.210340371976184f * (float)(j & ~1) * (1.0f / 128.0f));
    float ang = (float)p * div;
    peT[id] = (j & 1) ? cosf(ang) : sinf(ang);
    return;
  }
  unsigned i = id - 16384u;
  if (i >= 1310720u) return;
  if (i < 65536u) {
    unsigned oc = i >> 8, ch = i & 255u;
    pwqs[pack_idx(oc + 256u, ch, 8u)] = f2b(spw[i]);
  } else if (i < 131072u) {
    wop[i - 65536u] = f2b(opw[i - 65536u]);
  } else {
    unsigned r = i - 131072u;
    unsigned e = r & 7u, l = (r >> 3) & 63u, rt = (r >> 9) & 3u;
    unsigned idx3 = r >> 11;
    unsigned tap = idx3 % 9u, q = idx3 / 9u;
    unsigned ocb = q & 3u, cc = q >> 2;
    unsigned oc = ocb * 64u + rt * 16u + (l & 15u);
    unsigned ic = cc * 32u + (l >> 4) * 8u + e;
    wc[r] = f2b(postw[(oc * 512u + ic) * 9u + tap]);
  }
}

// ================= fold: combined weights (packed) + PE tables =================
__global__ void k_fold(const float* __restrict__ qpw, const float* __restrict__ kpw,
                       const float* __restrict__ vpw, const float* __restrict__ inw,
                       const float* __restrict__ inb, const float* __restrict__ peT,
                       unsigned short* __restrict__ pwqs, unsigned short* __restrict__ pwk,
                       unsigned short* __restrict__ pwv, float* __restrict__ tb) {
  __shared__ float wrow[256];
  const int tid = threadIdx.x, bid = blockIdx.x;
  if (bid < 768) {
    int m = bid >> 8;                 // 0 q, 1 k, 2 v
    int e2 = bid & 255;
    wrow[tid] = inw[(m * 256 + e2) * 256 + tid];
    __syncthreads();
    if (m == 1) {
      float a0 = 0.f, a1 = 0.f;
      for (int e = 0; e < 256; ++e) {
        float s = wrow[e];
        a0 = fmaf(s, kpw[e * 512 + tid], a0);
        a1 = fmaf(s, kpw[e * 512 + 256 + tid], a1);
      }
      pwk[pack_idx(e2, tid, 4u)] = f2b(a0);
      pwk[pack_idx(e2, tid + 256, 4u)] = f2b(a1);
    } else {
      const float* pw = (m == 0) ? qpw : vpw;
      float a0 = 0.f;
      for (int e = 0; e < 256; ++e) a0 = fmaf(wrow[e], pw[e * 256 + tid], a0);
      if (m == 0) pwqs[pack_idx(e2, tid, 8u)] = f2b(a0);
      else        pwv[pack_idx(e2, tid, 4u)] = f2b(a0);
    }
  } else {
    int r = bid - 768;
    int t = r >> 7, p = r & 127;      // t: 0 Aq,1 Bq,2 Ak,3 Bk,4 Av,5 Bv
    if (tid < 128) wrow[tid] = peT[p * 128 + tid];
    __syncthreads();
    int woff = (t >> 1) * 256, joff = (t & 1) * 128;
    float acc = (t & 1) ? 0.f : inb[woff + tid];
    const float* wr = inw + (size_t)(woff + tid) * 256 + joff;
    for (int j = 0; j < 128; ++j) acc = fmaf(wrow[j], wr[j], acc);
    tb[t * 32768 + p * 256 + tid] = acc;
  }
}

// ================= shared GEMM (k_wattn): OUT[e][tok] += W[e][c] * X[tok][c] ===========
__device__ __forceinline__ void gemm4x4(f32x4 acc[4][4], const unsigned short* __restrict__ wA,
                                        int Kw, int kw0, const unsigned short* sB, int strideB,
                                        int nK, int wid, int lane) {
  const int rA = lane & 15;
  const int kq = (lane >> 4) << 3;
  for (int ks = 0; ks < nK; ks += 32) {
    bf16x8 a[4];
#pragma unroll
    for (int rt = 0; rt < 4; ++rt)
      a[rt] = *reinterpret_cast<const bf16x8*>(wA + (wid * 64 + rt * 16 + rA) * Kw + kw0 + ks + kq);
#pragma unroll
    for (int ct = 0; ct < 4; ++ct) {
      bf16x8 bb = rd8(sB, ct * 16 + rA, strideB, ks + kq);
#pragma unroll
      for (int rt = 0; rt < 4; ++rt) acc[rt][ct] = MFMA16(a[rt], bb, acc[rt][ct]);
    }
  }
}

// y_t layout: [b][cc=ch/32][h][w][ch%32]
__device__ __forceinline__ void epi_global(unsigned short* __restrict__ y_t, const f32x4 acc[4][4],
                                           const float* __restrict__ bias, int chOff,
                                           int b, int h0, int w0, int wid, int lane) {
#pragma unroll
  for (int rt = 0; rt < 4; ++rt) {
    int e0 = wid * 64 + rt * 16 + ((lane >> 4) << 2);
    float4 bs = bias ? *reinterpret_cast<const float4*>(bias + e0) : make_float4(0.f, 0.f, 0.f, 0.f);
    int ch = chOff + e0;
#pragma unroll
    for (int ct = 0; ct < 4; ++ct) {
      int tok = ct * 16 + (lane & 15);
      int r = tok >> 3, cpx = tok & 7;
      long gy = ((((long)(b * 16 + (ch >> 5)) * 128 + (h0 + r)) * 128 + (w0 + cpx)) << 5) + (ch & 31);
      ushort4 pk;
      pk.x = f2b(acc[rt][ct][0] + bs.x);
      pk.y = f2b(acc[rt][ct][1] + bs.y);
      pk.z = f2b(acc[rt][ct][2] + bs.z);
      pk.w = f2b(acc[rt][ct][3] + bs.w);
      *reinterpret_cast<ushort4*>(y_t + gy) = pk;
    }
  }
}

// ================= projections v4: stage-once full-K, 3 units/tile =================
// block = 512 thr / 8 waves; tile = 128 tok (8h x 16w = 2 windows)
// unit 0: qs (d1, 512 oc: q moG 0..3 + skip moG 4..7, 2 tiles/wave)
// unit 1: k  (x5, 256 oc, K=512 in 2 phases)   unit 2: v (d2, 256 oc)
// LDS [128 tok][258]: stride-258 (rot 1 bank/row) + 16B-block perm p(g)=((g&1)<<2)|(g>>1)
__launch_bounds__(512, 4)
__global__ void k_proj(const float* __restrict__ x5, const float* __restrict__ d1,
                       const float* __restrict__ d2,
                       const unsigned short* __restrict__ pwqs, const unsigned short* __restrict__ pwk,
                       const unsigned short* __restrict__ pwv, const float* __restrict__ tb,
                       unsigned short* __restrict__ qh, unsigned short* __restrict__ kh,
                       unsigned short* __restrict__ vt, unsigned short* __restrict__ y_t) {
  extern __shared__ unsigned short sB[];   // [128][258]
  const int tid = threadIdx.x, l = tid & 63, wv = tid >> 6;
  const int l15 = l & 15, gq = l >> 4;
  const int braw = blockIdx.x;
  const int bid = (braw & 7) * 384 + (braw >> 3);      // XCD-grouped
  const int unit = bid >> 10, tile = bid & 1023;
  const int wt = tile & 7, hs = (tile >> 3) & 15, b = tile >> 7;
  const int h0 = hs * 8, w0 = wt * 16;
  const int win = wv & 1, og = wv >> 1;                // 2 win x 4 og waves

  const float* src; const unsigned short* wf; int Mdiv, Cin;
  if (unit == 0)      { src = d1; wf = pwqs; Mdiv = 8; Cin = 256; }
  else if (unit == 1) { src = x5; wf = pwk;  Mdiv = 4; Cin = 512; }
  else                { src = d2; wf = pwv;  Mdiv = 4; Cin = 256; }

  // ---- staging thread map: tokq = 4-px group (same h row), ch16 = 16-ch group ----
  const int tokq = tid & 31, ch16 = tid >> 5;
  const long pxoff = (long)(h0 + (tokq >> 2)) * 128 + w0 + (tokq & 3) * 4;
  // LDS row for px e: window-major token order
  const int rowb = ((tokq & 3) >> 1) * 64 + (tokq >> 2) * 8 + (tokq & 1) * 4;

  auto stage_half = [&](int chOff, int c2) {
    float4 pv[8];
    const float* sp = src + (((long)(b * Cin + chOff + ch16 * 16 + c2 * 8)) << 14) + pxoff;
#pragma unroll
    for (int uu = 0; uu < 8; ++uu)
      pv[uu] = *reinterpret_cast<const float4*>(sp + ((long)uu << 14));
    const int bb = ch16 * 2 + c2, group = bb >> 3, g = bb & 7;
    const int colbase = (group << 6) + ((((g & 1) << 2) | (g >> 1)) << 3);
#pragma unroll
    for (int e = 0; e < 4; ++e) {
      bf16x8 pk;
#pragma unroll
      for (int uu = 0; uu < 8; ++uu)
        ((unsigned short*)&pk)[uu] = f2b(reinterpret_cast<const float*>(&pv[uu])[e]);
      *reinterpret_cast<bf16x8*>(&sB[(rowb + e) * 258 + colbase]) = pk;
    }
  };

  // ---- compute-side LDS addressing ----
  int bRow[4];
#pragma unroll
  for (int ct = 0; ct < 4; ++ct) bRow[ct] = (win * 64 + ct * 16 + l15) * 258;
  const int p0 = (((gq & 1) << 2) | (gq >> 1)) << 3;   // ksi=0 block offset (shorts)

  const f32x4 vz = {0.f, 0.f, 0.f, 0.f};
  f32x4 acc[4][4];

  auto zacc = [&]() {
#pragma unroll
    for (int rt = 0; rt < 4; ++rt)
#pragma unroll
      for (int ct = 0; ct < 4; ++ct) acc[rt][ct] = vz;
  };

  auto run_tile = [&](int moG, int kc0, int kcn) {
    for (int kc = kc0; kc < kc0 + kcn; ++kc) {
      const unsigned short* pa = wf + (((kc * Mdiv + moG) << 12) | (l << 3));
      const int kcL = (kc & 3) << 6;
#pragma unroll
      for (int ksi = 0; ksi < 2; ++ksi) {
        bf16x8 a[4];
#pragma unroll
        for (int rt = 0; rt < 4; ++rt)
          a[rt] = *reinterpret_cast<const bf16x8*>(pa + ((rt * 2 + ksi) << 9));
#pragma unroll
        for (int ct = 0; ct < 4; ++ct) {
          bf16x8 bb = *reinterpret_cast<const bf16x8*>(&sB[bRow[ct] + kcL + p0 + ksi * 16]);
#pragma unroll
          for (int rt = 0; rt < 4; ++rt) acc[rt][ct] = MFMA16(a[rt], bb, acc[rt][ct]);
        }
      }
    }
  };

  const int win_g = ((b * 16 + hs) << 4) + wt * 2 + win;

  auto epi_qk = [&](int moG, int which) {   // which: 0=qh, 1=kh
    const float* At = tb + (which == 0 ? 0 : 65536);
    const float* Bt = tb + (which == 0 ? 32768 : 98304);
    unsigned short* dst = (which == 0 ? qh : kh) + ((size_t)win_g << 14);
#pragma unroll
    for (int rt = 0; rt < 4; ++rt) {
      int oc = moG * 64 + rt * 16 + gq * 4;
#pragma unroll
      for (int ct = 0; ct < 4; ++ct) {
        int wtok = ct * 16 + l15;
        int h = h0 + (wtok >> 3), wgl = w0 + win * 8 + (wtok & 7);
        float4 av = *reinterpret_cast<const float4*>(At + h * 256 + oc);
        float4 bv = *reinterpret_cast<const float4*>(Bt + wgl * 256 + oc);
        ushort4 pk;
        pk.x = f2b(acc[rt][ct][0] + av.x + bv.x);
        pk.y = f2b(acc[rt][ct][1] + av.y + bv.y);
        pk.z = f2b(acc[rt][ct][2] + av.z + bv.z);
        pk.w = f2b(acc[rt][ct][3] + av.w + bv.w);
        *reinterpret_cast<ushort4*>(dst + ((oc >> 5) << 11) + (wtok << 5) + (oc & 31)) = pk;
      }
    }
  };

  if (unit == 0) {
    stage_half(0, 0); stage_half(0, 1);
    __syncthreads();
    zacc();
    run_tile(og, 0, 4);
    epi_qk(og, 0);
    zacc();
    run_tile(4 + og, 0, 4);
    {  // skip -> y_t channels 256..511
      const int moG = 4 + og;
#pragma unroll
      for (int rt = 0; rt < 4; ++rt) {
        int ch = moG * 64 + rt * 16 + gq * 4;
        int cc = ch >> 5;
#pragma unroll
        for (int ct = 0; ct < 4; ++ct) {
          int wtok = ct * 16 + l15;
          int h = h0 + (wtok >> 3), wgl = w0 + win * 8 + (wtok & 7);
          long gy = ((((long)(b * 16 + cc) * 128 + h) * 128 + wgl) << 5) + (ch & 31);
          ushort4 pk;
          pk.x = f2b(acc[rt][ct][0]);
          pk.y = f2b(acc[rt][ct][1]);
          pk.z = f2b(acc[rt][ct][2]);
          pk.w = f2b(acc[rt][ct][3]);
          *reinterpret_cast<ushort4*>(y_t + gy) = pk;
        }
      }
    }
  } else if (unit == 1) {
    stage_half(0, 0); stage_half(0, 1);
    __syncthreads();
    zacc();
    run_tile(og, 0, 4);
    __syncthreads();                       // all waves done reading phase-1
    stage_half(256, 0); stage_half(256, 1);
    __syncthreads();
    run_tile(og, 4, 4);
    epi_qk(og, 1);
  } else {
    stage_half(0, 0); stage_half(0, 1);
    __syncthreads();
    zacc();
    run_tile(og, 0, 4);
    {  // vT epilogue
      const float* At = tb + 131072;
      const float* Bt = tb + 163840;
      unsigned short* dst = vt + ((size_t)win_g << 14);
#pragma unroll
      for (int rt = 0; rt < 4; ++rt) {
        int oc = og * 64 + rt * 16 + gq * 4;
        int hd = oc >> 5, chb = oc & 31;
#pragma unroll
        for (int ct = 0; ct < 4; ++ct) {
          int wtok = ct * 16 + l15;
          int h = h0 + (wtok >> 3), wgl = w0 + win * 8 + (wtok & 7);
          float4 av = *reinterpret_cast<const float4*>(At + h * 256 + oc);
          float4 bv = *reinterpret_cast<const float4*>(Bt + wgl * 256 + oc);
          const float* avf = reinterpret_cast<const float*>(&av);
          const float* bvf = reinterpret_cast<const float*>(&bv);
#pragma unroll
          for (int j = 0; j < 4; ++j)
            dst[(hd << 11) + (chb + j) * 64 + wtok] = f2b(acc[rt][ct][j] + avf[j] + bvf[j]);
        }
      }
    }
  }
}

// ================= window attention + out-proj (unchanged) =================
__launch_bounds__(256, 3)
__global__ void k_wattn(const unsigned short* __restrict__ qh, const unsigned short* __restrict__ kh,
                        const unsigned short* __restrict__ vt, const unsigned short* __restrict__ wop,
                        const float* __restrict__ out_b, unsigned short* __restrict__ y_t) {
  __shared__ unsigned short Pb[4096];
  __shared__ unsigned short bufO[16384];
  const int tid = threadIdx.x, lane = tid & 63, wid = tid >> 6;
  const int gq = lane >> 4, l15 = lane & 15, kq = gq << 3;
  const int bid = blockIdx.x;
  const int win = ((bid & 7) << 8) | (bid >> 3);
  const int b = win >> 8, wh = (win >> 4) & 15, ww = win & 15;
  const int h0 = wh * 8, w0 = ww * 8;

  const unsigned short* qw = qh + ((size_t)win << 14);
  const unsigned short* kw = kh + ((size_t)win << 14);
  const unsigned short* vw = vt + ((size_t)win << 14);

  const f32x4 vz = {0.f, 0.f, 0.f, 0.f};
  const float scl = 0.17677669529663687f;
  f32x4 o0[8], o1[8];
#pragma unroll
  for (int h = 0; h < 8; ++h) { o0[h] = vz; o1[h] = vz; }

#pragma unroll
  for (int hd = 0; hd < 8; ++hd) {
    const unsigned short* qb = qw + (hd << 11);
    const unsigned short* kb = kw + (hd << 11);
    const unsigned short* vb = vw + (hd << 11);
    bf16x8 aq = *reinterpret_cast<const bf16x8*>(qb + ((wid * 16 + l15) << 5) + kq);
    f32x4 sv[4];
#pragma unroll
    for (int ct = 0; ct < 4; ++ct) {
      bf16x8 bk = *reinterpret_cast<const bf16x8*>(kb + ((ct * 16 + l15) << 5) + kq);
      sv[ct] = MFMA16(aq, bk, vz);
    }
    float pr[4][4];
#pragma unroll
    for (int j = 0; j < 4; ++j) {
      float mx = fmaxf(fmaxf(sv[0][j], sv[1][j]), fmaxf(sv[2][j], sv[3][j])) * scl;
#pragma unroll
      for (int m = 8; m >= 1; m >>= 1) mx = fmaxf(mx, __shfl_xor(mx, m));
      float sum = 0.f;
#pragma unroll
      for (int ct = 0; ct < 4; ++ct) {
        float p = __expf(sv[ct][j] * scl - mx);
        pr[ct][j] = p;
        sum += p;
      }
#pragma unroll
      for (int m = 8; m >= 1; m >>= 1) sum += __shfl_xor(sum, m);
      float inv = 1.f / sum;
#pragma unroll
      for (int ct = 0; ct < 4; ++ct) pr[ct][j] *= inv;
    }
#pragma unroll
    for (int ct = 0; ct < 4; ++ct)
#pragma unroll
      for (int j = 0; j < 4; ++j) {
        int q = wid * 16 + gq * 4 + j;
        int kt = ct * 16 + l15;
        Pb[q * 64 + (kt ^ ((q & 7) << 3))] = f2b(pr[ct][j]);
      }
#pragma unroll
    for (int ks = 0; ks < 64; ks += 32) {
      bf16x8 bp = rd8(Pb, wid * 16 + l15, 64, ks + kq);
      bf16x8 a0 = *reinterpret_cast<const bf16x8*>(vb + (l15 << 6) + ks + kq);
      bf16x8 a1 = *reinterpret_cast<const bf16x8*>(vb + ((16 + l15) << 6) + ks + kq);
      o0[hd] = MFMA16(a0, bp, o0[hd]);
      o1[hd] = MFMA16(a1, bp, o1[hd]);
    }
  }

  {
    int tok = wid * 16 + l15;
    int sw = (tok & 7) << 3;
#pragma unroll
    for (int hd = 0; hd < 8; ++hd)
#pragma unroll
      for (int rt = 0; rt < 2; ++rt) {
        f32x4 ov = rt ? o1[hd] : o0[hd];
        int ch0 = hd * 32 + rt * 16 + gq * 4;
        ushort4 pk;
        pk.x = f2b(ov[0]); pk.y = f2b(ov[1]); pk.z = f2b(ov[2]); pk.w = f2b(ov[3]);
        *reinterpret_cast<ushort4*>(&bufO[tok * 256 + (ch0 ^ sw)]) = pk;
      }
  }
  __syncthreads();

  f32x4 accA[4][4];
#pragma unroll
  for (int i = 0; i < 4; ++i)
#pragma unroll
    for (int j = 0; j < 4; ++j) accA[i][j] = vz;
  gemm4x4(accA, wop, 256, 0, bufO, 256, 256, wid, lane);
  epi_global(y_t, accA, out_b, 0, b, h0, w0, wid, lane);
}

// ================= conv 3x3 (512->256) implicit GEMM (unchanged) =================
__device__ __forceinline__ void patch_load(const unsigned short* __restrict__ y_t,
                                           int b, int cc, int h0, int w0, int tid, uint4* pv) {
#pragma unroll
  for (int k = 0; k < 5; ++k) {
    int s = tid + (k << 9);
    uint4 v = make_uint4(0u, 0u, 0u, 0u);
    if (s < 2448) {
      int pr = (s * 482) >> 16;
      int rem = s - pr * 136;
      int pcpx = rem >> 2, g = rem & 3;
      int hh = h0 + pr - 1, wp = w0 + pcpx - 1;
      if ((unsigned)hh < 128u && (unsigned)wp < 128u)
        v = *reinterpret_cast<const uint4*>(
            y_t + ((((long)(b * 16 + cc) * 128 + hh) * 128 + wp) << 5) + (g << 3));
    }
    pv[k] = v;
  }
}

__device__ __forceinline__ void patch_store(unsigned short* buf, int tid, const uint4* pv) {
#pragma unroll
  for (int k = 0; k < 5; ++k) {
    int s = tid + (k << 9);
    if (s < 2448) {
      int pr = (s * 482) >> 16;
      int rem = s - pr * 136;
      int pcpx = rem >> 2, g = rem & 3;
      int pidx = pr * 34 + pcpx;
      *reinterpret_cast<uint4*>(buf + (pidx << 5) + ((g ^ ((pidx >> 1) & 3)) << 3)) = pv[k];
    }
  }
}

__device__ __forceinline__ void stage_A(const unsigned short* __restrict__ wA, int cc, int ocb,
                                        unsigned short* dstBase, int tid) {
  const unsigned short* src = wA + (size_t)(cc * 4 + ocb) * 18432 + tid * 8;
  unsigned short* dst = dstBase + tid * 8;
#pragma unroll
  for (int k = 0; k < 4; ++k) {
    __builtin_amdgcn_global_load_lds(
        (const __attribute__((address_space(1))) unsigned int*)(src + k * 4096),
        (__attribute__((address_space(3))) unsigned int*)(dst + k * 4096), 16, 0, 0);
  }
  if (tid < 256)
    __builtin_amdgcn_global_load_lds(
        (const __attribute__((address_space(1))) unsigned int*)(src + 16384),
        (__attribute__((address_space(3))) unsigned int*)(dst + 16384), 16, 0, 0);
}

__launch_bounds__(512, 2)
__global__ void k_conv(const unsigned short* __restrict__ y_t, const unsigned short* __restrict__ wc,
                       float* __restrict__ out) {
  extern __shared__ unsigned short cs[];
  unsigned short* Pb0 = cs;
  unsigned short* Pb1 = cs + 19584;
  unsigned short* Ab0 = cs + 39168;
  unsigned short* Ab1 = cs + 57600;

  const int tid = threadIdx.x, lane = tid & 63, pxg = tid >> 6;
  const int gq = lane >> 4, l15 = lane & 15;
  const int bi = ((int)blockIdx.x & 7) * 128 + ((int)blockIdx.x >> 3);
  const int ocb = bi & 3, wb = (bi >> 2) & 3, hb = (bi >> 4) & 7, b = bi >> 7;
  const int h0 = hb * 16, w0 = wb * 32;

  const f32x4 vz = {0.f, 0.f, 0.f, 0.f};
  f32x4 acc[4][4];
#pragma unroll
  for (int rt = 0; rt < 4; ++rt)
#pragma unroll
    for (int ct = 0; ct < 4; ++ct) acc[rt][ct] = vz;

  uint4 pv[5];
  patch_load(y_t, b, 0, h0, w0, tid, pv);
  stage_A(wc, 0, ocb, Ab0, tid);
  patch_store(Pb0, tid, pv);
  __syncthreads();

#pragma unroll 1
  for (int cc = 0; cc < 16; ++cc) {
    const unsigned short* pb = (cc & 1) ? Pb1 : Pb0;
    const unsigned short* pa = (cc & 1) ? Ab1 : Ab0;
    if (cc < 15) {
      patch_load(y_t, b, cc + 1, h0, w0, tid, pv);
      stage_A(wc, cc + 1, ocb, (cc & 1) ? Ab0 : Ab1, tid);
    }

#pragma unroll
    for (int kx = 0; kx < 3; ++kx) {
      bf16x8 bfr[4][2];
#pragma unroll
      for (int r = 0; r < 4; ++r)
#pragma unroll
        for (int ws = 0; ws < 2; ++ws) {
          int pidx = (pxg * 2 + r) * 34 + ws * 16 + l15 + kx;
          bfr[r][ws] = *reinterpret_cast<const bf16x8*>(
              pb + (pidx << 5) + ((gq ^ ((pidx >> 1) & 3)) << 3));
        }
      bf16x8 afr[3][4];
#pragma unroll
      for (int ky = 0; ky < 3; ++ky)
#pragma unroll
        for (int rt = 0; rt < 4; ++rt)
          afr[ky][rt] = *reinterpret_cast<const bf16x8*>(
              pa + (((ky * 3 + kx) * 4 + rt) << 9) + lane * 8);
#pragma unroll
      for (int ky = 0; ky < 3; ++ky)
#pragma unroll
        for (int ct = 0; ct < 4; ++ct) {
          int r = (ct >> 1) + ky, ws = ct & 1;
#pragma unroll
          for (int rt = 0; rt < 4; ++rt)
            acc[rt][ct] = MFMA16(afr[ky][rt], bfr[r][ws], acc[rt][ct]);
        }
    }

    if (cc < 15) patch_store((cc & 1) ? Pb0 : Pb1, tid, pv);
    __syncthreads();
  }

#pragma unroll
  for (int rt = 0; rt < 4; ++rt) {
    int oc0 = ocb * 64 + rt * 16 + gq * 4;
#pragma unroll
    for (int ct = 0; ct < 4; ++ct) {
      int hh = h0 + pxg * 2 + (ct >> 1), wp = w0 + ((ct & 1) << 4) + l15;
      long base = (((long)(b * 256 + oc0)) * 128 + hh) * 128 + wp;
#pragma unroll
      for (int j = 0; j < 4; ++j) out[base + (long)j * 16384] = acc[rt][ct][j];
    }
  }
}

// ================= BN stats / finalize / apply =================
__global__ void k_stats(const float* __restrict__ out, float* __restrict__ sums) {
  __shared__ float s1[256], s2[256];
  int c = blockIdx.x, tid = threadIdx.x;
  float a1 = 0.f, a2 = 0.f;
  for (int bb = 0; bb < 8; ++bb) {
    const float4* p = reinterpret_cast<const float4*>(out + ((long)(bb * 256 + c)) * 16384);
    for (int i = tid; i < 4096; i += 256) {
      float4 v = p[i];
      a1 += v.x + v.y + v.z + v.w;
      a2 += v.x * v.x + v.y * v.y + v.z * v.z + v.w * v.w;
    }
  }
  s1[tid] = a1; s2[tid] = a2;
  __syncthreads();
  for (int s = 128; s > 0; s >>= 1) {
    if (tid < s) { s1[tid] += s1[tid + s]; s2[tid] += s2[tid + s]; }
    __syncthreads();
  }
  if (tid == 0) { sums[c] = s1[0]; sums[256 + c] = s2[0]; }
}

__global__ void k_final(const float* __restrict__ sums, const float* __restrict__ gamma,
                        const float* __restrict__ beta, float* __restrict__ sc) {
  int c = threadIdx.x;
  float mean = sums[c] * (1.f / 131072.f);
  float var = sums[256 + c] * (1.f / 131072.f) - mean * mean;
  float s = gamma[c] * rsqrtf(var + 1e-5f);
  sc[c] = s;
  sc[256 + c] = beta[c] - mean * s;
}

__global__ void k_apply(float* __restrict__ out, const float* __restrict__ sc) {
  const long n4 = 33554432 / 4;
  for (long i4 = (long)blockIdx.x * 256 + threadIdx.x; i4 < n4; i4 += (long)gridDim.x * 256) {
    float4 v = reinterpret_cast<float4*>(out)[i4];
    int c = (int)((i4 >> 12) & 255);
    float s = sc[c], sh = sc[256 + c];
    v.x = fmaxf(v.x * s + sh, 0.f);
    v.y = fmaxf(v.y * s + sh, 0.f);
    v.z = fmaxf(v.z * s + sh, 0.f);
    v.w = fmaxf(v.w * s + sh, 0.f);
    reinterpret_cast<float4*>(out)[i4] = v;
  }
}

// ================= launch =================
extern "C" void kernel_launch(void* const* d_in, const int* in_sizes, int n_in,
                              void* d_out, int out_size, void* d_ws, size_t ws_size,
                              hipStream_t stream) {
  const float* x5 = (const float*)d_in[0];
  const float* d1 = (const float*)d_in[1];
  const float* d2 = (const float*)d_in[2];
  const float* kp = (const float*)d_in[3];
  const float* qp = (const float*)d_in[4];
  const float* vp = (const float*)d_in[5];
  const float* spw = (const float*)d_in[6];
  const float* inw = (const float*)d_in[7];
  const float* inb = (const float*)d_in[8];
  const float* opw = (const float*)d_in[9];
  const float* opb = (const float*)d_in[10];
  const float* pw = (const float*)d_in[11];
  const float* gamma = (const float*)d_in[12];
  const float* beta = (const float*)d_in[13];

  if (ws_size < (size_t)WSO_TOTAL) {
    fprintf(stderr, "kernel_launch: ws too small: %zu < %u\n", ws_size, WSO_TOTAL);
    return;
  }

  char* ws = (char*)d_ws;
  float* peT = (float*)(ws + WSO_PE);
  unsigned short* pwqs = (unsigned short*)(ws + WSO_PWQS);
  unsigned short* pwk = (unsigned short*)(ws + WSO_PWK);
  unsigned short* pwv = (unsigned short*)(ws + WSO_PWV);
  unsigned short* w_op = (unsigned short*)(ws + WSO_WOP);
  unsigned short* w_c = (unsigned short*)(ws + WSO_WC);
  float* tb = (float*)(ws + WSO_TB);
  unsigned short* qh = (unsigned short*)(ws + WSO_QH);
  unsigned short* kh = (unsigned short*)(ws + WSO_KH);
  unsigned short* vt = (unsigned short*)(ws + WSO_VT);
  unsigned short* y_t = (unsigned short*)(ws + WSO_YT);
  float* sums = (float*)(ws + WSO_SUMS);
  float* sc = (float*)(ws + WSO_SC);

  hipFuncSetAttribute(reinterpret_cast<const void*>(k_conv),
                      hipFuncAttributeMaxDynamicSharedMemorySize, SMEM_CONV);
  hipFuncSetAttribute(reinterpret_cast<const void*>(k_proj),
                      hipFuncAttributeMaxDynamicSharedMemorySize, SMEM_PROJ);

  k_prep<<<5184, 256, 0, stream>>>(spw, opw, pw, peT, pwqs, w_op, w_c);
  k_fold<<<1536, 256, 0, stream>>>(qp, kp, vp, inw, inb, peT, pwqs, pwk, pwv, tb);
  k_proj<<<3072, 512, SMEM_PROJ, stream>>>(x5, d1, d2, pwqs, pwk, pwv, tb, qh, kh, vt, y_t);
  k_wattn<<<2048, 256, 0, stream>>>(qh, kh, vt, w_op, opb, y_t);
  k_conv<<<1024, 512, SMEM_CONV, stream>>>(y_t, w_c, (float*)d_out);
  k_stats<<<256, 256, 0, stream>>>((const float*)d_out, sums);
  k_final<<<1, 256, 0, stream>>>(sums, gamma, beta, sc);
  k_apply<<<2048, 256, 0, stream>>>((float*)d_out, sc);
}

// Round 10
// 792.065 us; speedup vs baseline: 1.0093x; 1.0093x over previous
//
#include <hip/hip_runtime.h>
#include <cstdio>
#include <cmath>

typedef __attribute__((ext_vector_type(8))) short bf16x8;
typedef __attribute__((ext_vector_type(4))) float f32x4;

#define MFMA16(a, b, c) __builtin_amdgcn_mfma_f32_16x16x32_bf16((a), (b), (c), 0, 0, 0)

// ---------------- workspace layout (byte offsets) ----------------
#define WSO_PE    0u                          // float[128*128]
#define WSO_PWQS  65536u                      // bf16 packed [512][256]  (Wq@qp | sp)
#define WSO_PWK   (WSO_PWQS + 262144u)        // bf16 packed [256][512]  Wk@kp
#define WSO_PWV   (WSO_PWK + 262144u)         // bf16 packed [256][256]  Wv@vp
#define WSO_WOP   (WSO_PWV + 131072u)         // bf16 [256][256] row-major (k_wattn)
#define WSO_WC    (WSO_WOP + 131072u)         // bf16 conv fragment-packed
#define WSO_TB    (WSO_WC + 2359296u)         // bf16 [6][128][256] PE tables (bf16 now)
#define WSO_QH    (WSO_TB + 786432u)          // bf16 [2048][8][64][32]
#define WSO_KH    (WSO_QH + 67108864u)        // bf16 [2048][8][64][32]
#define WSO_VT    (WSO_KH + 67108864u)        // bf16 [2048][8][32][64]
#define WSO_YT    (WSO_VT + 67108864u)        // bf16 [8][16cc][128][128][32c]
#define WSO_SUMS  (WSO_YT + 134217728u)       // float[512]
#define WSO_SC    (WSO_SUMS + 2048u)          // float[512]
#define WSO_TOTAL (WSO_SC + 2048u)

#define SMEM_CONV 152064
#define SMEM_PROJ 66048   // dynamic part: 128 rows x 258 shorts x 2B (+12KB static tbl)

__device__ __forceinline__ unsigned short f2b(float x) {
  unsigned int u = __builtin_bit_cast(unsigned int, x);
  u += 0x7fffu + ((u >> 16) & 1u);
  return (unsigned short)(u >> 16);
}

__device__ __forceinline__ float b2f(unsigned short x) {
  return __builtin_bit_cast(float, ((unsigned int)x) << 16);
}

__device__ __forceinline__ bf16x8 rd8(const unsigned short* s, int row, int stride, int k) {
  return *reinterpret_cast<const bf16x8*>(s + row * stride + (k ^ ((row & 7) << 3)));
}

// fragment-pack index for MFMA A operands: [kc][moG][rt][ks][lane][8]
__device__ __forceinline__ unsigned pack_idx(unsigned oc, unsigned ch, unsigned Mdiv) {
  unsigned kc = ch >> 6, moG = oc >> 6, rt = (oc >> 4) & 3, ks = (ch >> 5) & 1;
  unsigned l = (oc & 15) | (((ch >> 3) & 3) << 4), e = ch & 7;
  return ((((kc * Mdiv + moG) * 4 + rt) * 2 + ks) * 64 + l) * 8 + e;
}

// ================= prep: pe table + weight conversions =================
__global__ void k_prep(const float* __restrict__ spw, const float* __restrict__ opw,
                       const float* __restrict__ postw,
                       float* __restrict__ peT, unsigned short* __restrict__ pwqs,
                       unsigned short* __restrict__ wop, unsigned short* __restrict__ wc) {
  unsigned id = blockIdx.x * 256u + threadIdx.x;
  if (id < 16384u) {
    int p = id >> 7, j = id & 127;
    float div = expf(-9.210340371976184f * (float)(j & ~1) * (1.0f / 128.0f));
    float ang = (float)p * div;
    peT[id] = (j & 1) ? cosf(ang) : sinf(ang);
    return;
  }
  unsigned i = id - 16384u;
  if (i >= 1310720u) return;
  if (i < 65536u) {
    unsigned oc = i >> 8, ch = i & 255u;
    pwqs[pack_idx(oc + 256u, ch, 8u)] = f2b(spw[i]);
  } else if (i < 131072u) {
    wop[i - 65536u] = f2b(opw[i - 65536u]);
  } else {
    unsigned r = i - 131072u;
    unsigned e = r & 7u, l = (r >> 3) & 63u, rt = (r >> 9) & 3u;
    unsigned idx3 = r >> 11;
    unsigned tap = idx3 % 9u, q = idx3 / 9u;
    unsigned ocb = q & 3u, cc = q >> 2;
    unsigned oc = ocb * 64u + rt * 16u + (l & 15u);
    unsigned ic = cc * 32u + (l >> 4) * 8u + e;
    wc[r] = f2b(postw[(oc * 512u + ic) * 9u + tap]);
  }
}

// ================= fold: combined weights (packed) + PE tables (bf16) =================
__global__ void k_fold(const float* __restrict__ qpw, const float* __restrict__ kpw,
                       const float* __restrict__ vpw, const float* __restrict__ inw,
                       const float* __restrict__ inb, const float* __restrict__ peT,
                       unsigned short* __restrict__ pwqs, unsigned short* __restrict__ pwk,
                       unsigned short* __restrict__ pwv, unsigned short* __restrict__ tbh) {
  __shared__ float wrow[256];
  const int tid = threadIdx.x, bid = blockIdx.x;
  if (bid < 768) {
    int m = bid >> 8;                 // 0 q, 1 k, 2 v
    int e2 = bid & 255;
    wrow[tid] = inw[(m * 256 + e2) * 256 + tid];
    __syncthreads();
    if (m == 1) {
      float a0 = 0.f, a1 = 0.f;
      for (int e = 0; e < 256; ++e) {
        float s = wrow[e];
        a0 = fmaf(s, kpw[e * 512 + tid], a0);
        a1 = fmaf(s, kpw[e * 512 + 256 + tid], a1);
      }
      pwk[pack_idx(e2, tid, 4u)] = f2b(a0);
      pwk[pack_idx(e2, tid + 256, 4u)] = f2b(a1);
    } else {
      const float* pw = (m == 0) ? qpw : vpw;
      float a0 = 0.f;
      for (int e = 0; e < 256; ++e) a0 = fmaf(wrow[e], pw[e * 256 + tid], a0);
      if (m == 0) pwqs[pack_idx(e2, tid, 8u)] = f2b(a0);
      else        pwv[pack_idx(e2, tid, 4u)] = f2b(a0);
    }
  } else {
    int r = bid - 768;
    int t = r >> 7, p = r & 127;      // t: 0 Aq,1 Bq,2 Ak,3 Bk,4 Av,5 Bv
    if (tid < 128) wrow[tid] = peT[p * 128 + tid];
    __syncthreads();
    int woff = (t >> 1) * 256, joff = (t & 1) * 128;
    float acc = (t & 1) ? 0.f : inb[woff + tid];
    const float* wr = inw + (size_t)(woff + tid) * 256 + joff;
    for (int j = 0; j < 128; ++j) acc = fmaf(wrow[j], wr[j], acc);
    tbh[t * 32768 + p * 256 + tid] = f2b(acc);
  }
}

// ================= shared GEMM (k_wattn): OUT[e][tok] += W[e][c] * X[tok][c] ===========
__device__ __forceinline__ void gemm4x4(f32x4 acc[4][4], const unsigned short* __restrict__ wA,
                                        int Kw, int kw0, const unsigned short* sB, int strideB,
                                        int nK, int wid, int lane) {
  const int rA = lane & 15;
  const int kq = (lane >> 4) << 3;
  for (int ks = 0; ks < nK; ks += 32) {
    bf16x8 a[4];
#pragma unroll
    for (int rt = 0; rt < 4; ++rt)
      a[rt] = *reinterpret_cast<const bf16x8*>(wA + (wid * 64 + rt * 16 + rA) * Kw + kw0 + ks + kq);
#pragma unroll
    for (int ct = 0; ct < 4; ++ct) {
      bf16x8 bb = rd8(sB, ct * 16 + rA, strideB, ks + kq);
#pragma unroll
      for (int rt = 0; rt < 4; ++rt) acc[rt][ct] = MFMA16(a[rt], bb, acc[rt][ct]);
    }
  }
}

// y_t layout: [b][cc=ch/32][h][w][ch%32]
__device__ __forceinline__ void epi_global(unsigned short* __restrict__ y_t, const f32x4 acc[4][4],
                                           const float* __restrict__ bias, int chOff,
                                           int b, int h0, int w0, int wid, int lane) {
#pragma unroll
  for (int rt = 0; rt < 4; ++rt) {
    int e0 = wid * 64 + rt * 16 + ((lane >> 4) << 2);
    float4 bs = bias ? *reinterpret_cast<const float4*>(bias + e0) : make_float4(0.f, 0.f, 0.f, 0.f);
    int ch = chOff + e0;
#pragma unroll
    for (int ct = 0; ct < 4; ++ct) {
      int tok = ct * 16 + (lane & 15);
      int r = tok >> 3, cpx = tok & 7;
      long gy = ((((long)(b * 16 + (ch >> 5)) * 128 + (h0 + r)) * 128 + (w0 + cpx)) << 5) + (ch & 31);
      ushort4 pk;
      pk.x = f2b(acc[rt][ct][0] + bs.x);
      pk.y = f2b(acc[rt][ct][1] + bs.y);
      pk.z = f2b(acc[rt][ct][2] + bs.z);
      pk.w = f2b(acc[rt][ct][3] + bs.w);
      *reinterpret_cast<ushort4*>(y_t + gy) = pk;
    }
  }
}

// ================= projections v5: v4 + LDS-staged bf16 PE tables =================
// block = 512 thr / 8 waves; tile = 128 tok (8h x 16w = 2 windows)
// unit 0: qs (d1, q moG 0..3 + skip moG 4..7)  unit 1: k (x5, 2 phases)  unit 2: v (d2)
// tbl LDS [24][256] bf16: rows 0-7 = A[h0+r], rows 8-23 = B[w0+r] (both windows)
__launch_bounds__(512, 4)
__global__ void k_proj(const float* __restrict__ x5, const float* __restrict__ d1,
                       const float* __restrict__ d2,
                       const unsigned short* __restrict__ pwqs, const unsigned short* __restrict__ pwk,
                       const unsigned short* __restrict__ pwv, const unsigned short* __restrict__ tbh,
                       unsigned short* __restrict__ qh, unsigned short* __restrict__ kh,
                       unsigned short* __restrict__ vt, unsigned short* __restrict__ y_t) {
  extern __shared__ unsigned short sB[];   // [128][258]
  __shared__ unsigned short tbl[6144];     // [24][256] bf16 PE tables
  const int tid = threadIdx.x, l = tid & 63, wv = tid >> 6;
  const int l15 = l & 15, gq = l >> 4;
  const int braw = blockIdx.x;
  const int bid = (braw & 7) * 384 + (braw >> 3);      // XCD-grouped
  const int unit = bid >> 10, tile = bid & 1023;
  const int wt = tile & 7, hs = (tile >> 3) & 15, b = tile >> 7;
  const int h0 = hs * 8, w0 = wt * 16;
  const int win = wv & 1, og = wv >> 1;                // 2 win x 4 og waves

  const float* src; const unsigned short* wf; int Mdiv, Cin;
  if (unit == 0)      { src = d1; wf = pwqs; Mdiv = 8; Cin = 256; }
  else if (unit == 1) { src = x5; wf = pwk;  Mdiv = 4; Cin = 512; }
  else                { src = d2; wf = pwv;  Mdiv = 4; Cin = 256; }

  // ---- stage PE tables for this unit (coalesced; read at epilogue from LDS) ----
  {
    const unsigned short* tA = tbh + (unit * 2) * 32768;
    const unsigned short* tB = tA + 32768;
#pragma unroll
    for (int k = 0; k < 3; ++k) {
      int v = tid + (k << 9);
      int row24 = v >> 6, ch4 = (v & 63) << 2;
      const unsigned short* s = (row24 < 8) ? (tA + (h0 + row24) * 256 + ch4)
                                            : (tB + (w0 + row24 - 8) * 256 + ch4);
      *reinterpret_cast<ushort4*>(&tbl[row24 * 256 + ch4]) = *reinterpret_cast<const ushort4*>(s);
    }
  }

  // ---- staging thread map: tokq = 4-px group (same h row), ch16 = 16-ch group ----
  const int tokq = tid & 31, ch16 = tid >> 5;
  const long pxoff = (long)(h0 + (tokq >> 2)) * 128 + w0 + (tokq & 3) * 4;
  const int rowb = ((tokq & 3) >> 1) * 64 + (tokq >> 2) * 8 + (tokq & 1) * 4;

  auto stage_half = [&](int chOff, int c2) {
    float4 pv[8];
    const float* sp = src + (((long)(b * Cin + chOff + ch16 * 16 + c2 * 8)) << 14) + pxoff;
#pragma unroll
    for (int uu = 0; uu < 8; ++uu)
      pv[uu] = *reinterpret_cast<const float4*>(sp + ((long)uu << 14));
    const int bb = ch16 * 2 + c2, group = bb >> 3, g = bb & 7;
    const int colbase = (group << 6) + ((((g & 1) << 2) | (g >> 1)) << 3);
#pragma unroll
    for (int e = 0; e < 4; ++e) {
      bf16x8 pk;
#pragma unroll
      for (int uu = 0; uu < 8; ++uu)
        ((unsigned short*)&pk)[uu] = f2b(reinterpret_cast<const float*>(&pv[uu])[e]);
      *reinterpret_cast<bf16x8*>(&sB[(rowb + e) * 258 + colbase]) = pk;
    }
  };

  // ---- compute-side LDS addressing ----
  int bRow[4];
#pragma unroll
  for (int ct = 0; ct < 4; ++ct) bRow[ct] = (win * 64 + ct * 16 + l15) * 258;
  const int p0 = (((gq & 1) << 2) | (gq >> 1)) << 3;   // ksi=0 block offset (shorts)

  const f32x4 vz = {0.f, 0.f, 0.f, 0.f};
  f32x4 acc[4][4];

  auto zacc = [&]() {
#pragma unroll
    for (int rt = 0; rt < 4; ++rt)
#pragma unroll
      for (int ct = 0; ct < 4; ++ct) acc[rt][ct] = vz;
  };

  auto run_tile = [&](int moG, int kc0, int kcn) {
    for (int kc = kc0; kc < kc0 + kcn; ++kc) {
      const unsigned short* pa = wf + (((kc * Mdiv + moG) << 12) | (l << 3));
      const int kcL = (kc & 3) << 6;
#pragma unroll
      for (int ksi = 0; ksi < 2; ++ksi) {
        bf16x8 a[4];
#pragma unroll
        for (int rt = 0; rt < 4; ++rt)
          a[rt] = *reinterpret_cast<const bf16x8*>(pa + ((rt * 2 + ksi) << 9));
#pragma unroll
        for (int ct = 0; ct < 4; ++ct) {
          bf16x8 bb = *reinterpret_cast<const bf16x8*>(&sB[bRow[ct] + kcL + p0 + ksi * 16]);
#pragma unroll
          for (int rt = 0; rt < 4; ++rt) acc[rt][ct] = MFMA16(a[rt], bb, acc[rt][ct]);
        }
      }
    }
  };

  const int win_g = ((b * 16 + hs) << 4) + wt * 2 + win;

  auto epi_qk = [&](int moG, int which) {   // which: 0=qh, 1=kh; tables from LDS
    unsigned short* dst = (which == 0 ? qh : kh) + ((size_t)win_g << 14);
#pragma unroll
    for (int rt = 0; rt < 4; ++rt) {
      int oc = moG * 64 + rt * 16 + gq * 4;
#pragma unroll
      for (int ct = 0; ct < 4; ++ct) {
        int wtok = ct * 16 + l15;
        ushort4 av = *reinterpret_cast<const ushort4*>(&tbl[(wtok >> 3) * 256 + oc]);
        ushort4 bv = *reinterpret_cast<const ushort4*>(
            &tbl[(8 + win * 8 + (wtok & 7)) * 256 + oc]);
        ushort4 pk;
        pk.x = f2b(acc[rt][ct][0] + b2f(av.x) + b2f(bv.x));
        pk.y = f2b(acc[rt][ct][1] + b2f(av.y) + b2f(bv.y));
        pk.z = f2b(acc[rt][ct][2] + b2f(av.z) + b2f(bv.z));
        pk.w = f2b(acc[rt][ct][3] + b2f(av.w) + b2f(bv.w));
        *reinterpret_cast<ushort4*>(dst + ((oc >> 5) << 11) + (wtok << 5) + (oc & 31)) = pk;
      }
    }
  };

  if (unit == 0) {
    stage_half(0, 0); stage_half(0, 1);
    __syncthreads();
    zacc();
    run_tile(og, 0, 4);
    epi_qk(og, 0);
    zacc();
    run_tile(4 + og, 0, 4);
    {  // skip -> y_t channels 256..511 (no tables)
      const int moG = 4 + og;
#pragma unroll
      for (int rt = 0; rt < 4; ++rt) {
        int ch = moG * 64 + rt * 16 + gq * 4;
        int cc = ch >> 5;
#pragma unroll
        for (int ct = 0; ct < 4; ++ct) {
          int wtok = ct * 16 + l15;
          int h = h0 + (wtok >> 3), wgl = w0 + win * 8 + (wtok & 7);
          long gy = ((((long)(b * 16 + cc) * 128 + h) * 128 + wgl) << 5) + (ch & 31);
          ushort4 pk;
          pk.x = f2b(acc[rt][ct][0]);
          pk.y = f2b(acc[rt][ct][1]);
          pk.z = f2b(acc[rt][ct][2]);
          pk.w = f2b(acc[rt][ct][3]);
          *reinterpret_cast<ushort4*>(y_t + gy) = pk;
        }
      }
    }
  } else if (unit == 1) {
    stage_half(0, 0); stage_half(0, 1);
    __syncthreads();
    zacc();
    run_tile(og, 0, 4);
    __syncthreads();                       // all waves done reading phase-1
    stage_half(256, 0); stage_half(256, 1);
    __syncthreads();
    run_tile(og, 4, 4);
    epi_qk(og, 1);
  } else {
    stage_half(0, 0); stage_half(0, 1);
    __syncthreads();
    zacc();
    run_tile(og, 0, 4);
    {  // vT epilogue (tables from LDS)
      unsigned short* dst = vt + ((size_t)win_g << 14);
#pragma unroll
      for (int rt = 0; rt < 4; ++rt) {
        int oc = og * 64 + rt * 16 + gq * 4;
        int hd = oc >> 5, chb = oc & 31;
#pragma unroll
        for (int ct = 0; ct < 4; ++ct) {
          int wtok = ct * 16 + l15;
          ushort4 av = *reinterpret_cast<const ushort4*>(&tbl[(wtok >> 3) * 256 + oc]);
          ushort4 bv = *reinterpret_cast<const ushort4*>(
              &tbl[(8 + win * 8 + (wtok & 7)) * 256 + oc]);
          const unsigned short* avp = reinterpret_cast<const unsigned short*>(&av);
          const unsigned short* bvp = reinterpret_cast<const unsigned short*>(&bv);
#pragma unroll
          for (int j = 0; j < 4; ++j)
            dst[(hd << 11) + (chb + j) * 64 + wtok] = f2b(acc[rt][ct][j] + b2f(avp[j]) + b2f(bvp[j]));
        }
      }
    }
  }
}

// ================= window attention + out-proj (unchanged) =================
__launch_bounds__(256, 3)
__global__ void k_wattn(const unsigned short* __restrict__ qh, const unsigned short* __restrict__ kh,
                        const unsigned short* __restrict__ vt, const unsigned short* __restrict__ wop,
                        const float* __restrict__ out_b, unsigned short* __restrict__ y_t) {
  __shared__ unsigned short Pb[4096];
  __shared__ unsigned short bufO[16384];
  const int tid = threadIdx.x, lane = tid & 63, wid = tid >> 6;
  const int gq = lane >> 4, l15 = lane & 15, kq = gq << 3;
  const int bid = blockIdx.x;
  const int win = ((bid & 7) << 8) | (bid >> 3);
  const int b = win >> 8, wh = (win >> 4) & 15, ww = win & 15;
  const int h0 = wh * 8, w0 = ww * 8;

  const unsigned short* qw = qh + ((size_t)win << 14);
  const unsigned short* kw = kh + ((size_t)win << 14);
  const unsigned short* vw = vt + ((size_t)win << 14);

  const f32x4 vz = {0.f, 0.f, 0.f, 0.f};
  const float scl = 0.17677669529663687f;
  f32x4 o0[8], o1[8];
#pragma unroll
  for (int h = 0; h < 8; ++h) { o0[h] = vz; o1[h] = vz; }

#pragma unroll
  for (int hd = 0; hd < 8; ++hd) {
    const unsigned short* qb = qw + (hd << 11);
    const unsigned short* kb = kw + (hd << 11);
    const unsigned short* vb = vw + (hd << 11);
    bf16x8 aq = *reinterpret_cast<const bf16x8*>(qb + ((wid * 16 + l15) << 5) + kq);
    f32x4 sv[4];
#pragma unroll
    for (int ct = 0; ct < 4; ++ct) {
      bf16x8 bk = *reinterpret_cast<const bf16x8*>(kb + ((ct * 16 + l15) << 5) + kq);
      sv[ct] = MFMA16(aq, bk, vz);
    }
    float pr[4][4];
#pragma unroll
    for (int j = 0; j < 4; ++j) {
      float mx = fmaxf(fmaxf(sv[0][j], sv[1][j]), fmaxf(sv[2][j], sv[3][j])) * scl;
#pragma unroll
      for (int m = 8; m >= 1; m >>= 1) mx = fmaxf(mx, __shfl_xor(mx, m));
      float sum = 0.f;
#pragma unroll
      for (int ct = 0; ct < 4; ++ct) {
        float p = __expf(sv[ct][j] * scl - mx);
        pr[ct][j] = p;
        sum += p;
      }
#pragma unroll
      for (int m = 8; m >= 1; m >>= 1) sum += __shfl_xor(sum, m);
      float inv = 1.f / sum;
#pragma unroll
      for (int ct = 0; ct < 4; ++ct) pr[ct][j] *= inv;
    }
#pragma unroll
    for (int ct = 0; ct < 4; ++ct)
#pragma unroll
      for (int j = 0; j < 4; ++j) {
        int q = wid * 16 + gq * 4 + j;
        int kt = ct * 16 + l15;
        Pb[q * 64 + (kt ^ ((q & 7) << 3))] = f2b(pr[ct][j]);
      }
#pragma unroll
    for (int ks = 0; ks < 64; ks += 32) {
      bf16x8 bp = rd8(Pb, wid * 16 + l15, 64, ks + kq);
      bf16x8 a0 = *reinterpret_cast<const bf16x8*>(vb + (l15 << 6) + ks + kq);
      bf16x8 a1 = *reinterpret_cast<const bf16x8*>(vb + ((16 + l15) << 6) + ks + kq);
      o0[hd] = MFMA16(a0, bp, o0[hd]);
      o1[hd] = MFMA16(a1, bp, o1[hd]);
    }
  }

  {
    int tok = wid * 16 + l15;
    int sw = (tok & 7) << 3;
#pragma unroll
    for (int hd = 0; hd < 8; ++hd)
#pragma unroll
      for (int rt = 0; rt < 2; ++rt) {
        f32x4 ov = rt ? o1[hd] : o0[hd];
        int ch0 = hd * 32 + rt * 16 + gq * 4;
        ushort4 pk;
        pk.x = f2b(ov[0]); pk.y = f2b(ov[1]); pk.z = f2b(ov[2]); pk.w = f2b(ov[3]);
        *reinterpret_cast<ushort4*>(&bufO[tok * 256 + (ch0 ^ sw)]) = pk;
      }
  }
  __syncthreads();

  f32x4 accA[4][4];
#pragma unroll
  for (int i = 0; i < 4; ++i)
#pragma unroll
    for (int j = 0; j < 4; ++j) accA[i][j] = vz;
  gemm4x4(accA, wop, 256, 0, bufO, 256, 256, wid, lane);
  epi_global(y_t, accA, out_b, 0, b, h0, w0, wid, lane);
}

// ================= conv 3x3 (512->256) implicit GEMM (unchanged) =================
__device__ __forceinline__ void patch_load(const unsigned short* __restrict__ y_t,
                                           int b, int cc, int h0, int w0, int tid, uint4* pv) {
#pragma unroll
  for (int k = 0; k < 5; ++k) {
    int s = tid + (k << 9);
    uint4 v = make_uint4(0u, 0u, 0u, 0u);
    if (s < 2448) {
      int pr = (s * 482) >> 16;
      int rem = s - pr * 136;
      int pcpx = rem >> 2, g = rem & 3;
      int hh = h0 + pr - 1, wp = w0 + pcpx - 1;
      if ((unsigned)hh < 128u && (unsigned)wp < 128u)
        v = *reinterpret_cast<const uint4*>(
            y_t + ((((long)(b * 16 + cc) * 128 + hh) * 128 + wp) << 5) + (g << 3));
    }
    pv[k] = v;
  }
}

__device__ __forceinline__ void patch_store(unsigned short* buf, int tid, const uint4* pv) {
#pragma unroll
  for (int k = 0; k < 5; ++k) {
    int s = tid + (k << 9);
    if (s < 2448) {
      int pr = (s * 482) >> 16;
      int rem = s - pr * 136;
      int pcpx = rem >> 2, g = rem & 3;
      int pidx = pr * 34 + pcpx;
      *reinterpret_cast<uint4*>(buf + (pidx << 5) + ((g ^ ((pidx >> 1) & 3)) << 3)) = pv[k];
    }
  }
}

__device__ __forceinline__ void stage_A(const unsigned short* __restrict__ wA, int cc, int ocb,
                                        unsigned short* dstBase, int tid) {
  const unsigned short* src = wA + (size_t)(cc * 4 + ocb) * 18432 + tid * 8;
  unsigned short* dst = dstBase + tid * 8;
#pragma unroll
  for (int k = 0; k < 4; ++k) {
    __builtin_amdgcn_global_load_lds(
        (const __attribute__((address_space(1))) unsigned int*)(src + k * 4096),
        (__attribute__((address_space(3))) unsigned int*)(dst + k * 4096), 16, 0, 0);
  }
  if (tid < 256)
    __builtin_amdgcn_global_load_lds(
        (const __attribute__((address_space(1))) unsigned int*)(src + 16384),
        (__attribute__((address_space(3))) unsigned int*)(dst + 16384), 16, 0, 0);
}

__launch_bounds__(512, 2)
__global__ void k_conv(const unsigned short* __restrict__ y_t, const unsigned short* __restrict__ wc,
                       float* __restrict__ out) {
  extern __shared__ unsigned short cs[];
  unsigned short* Pb0 = cs;
  unsigned short* Pb1 = cs + 19584;
  unsigned short* Ab0 = cs + 39168;
  unsigned short* Ab1 = cs + 57600;

  const int tid = threadIdx.x, lane = tid & 63, pxg = tid >> 6;
  const int gq = lane >> 4, l15 = lane & 15;
  const int bi = ((int)blockIdx.x & 7) * 128 + ((int)blockIdx.x >> 3);
  const int ocb = bi & 3, wb = (bi >> 2) & 3, hb = (bi >> 4) & 7, b = bi >> 7;
  const int h0 = hb * 16, w0 = wb * 32;

  const f32x4 vz = {0.f, 0.f, 0.f, 0.f};
  f32x4 acc[4][4];
#pragma unroll
  for (int rt = 0; rt < 4; ++rt)
#pragma unroll
    for (int ct = 0; ct < 4; ++ct) acc[rt][ct] = vz;

  uint4 pv[5];
  patch_load(y_t, b, 0, h0, w0, tid, pv);
  stage_A(wc, 0, ocb, Ab0, tid);
  patch_store(Pb0, tid, pv);
  __syncthreads();

#pragma unroll 1
  for (int cc = 0; cc < 16; ++cc) {
    const unsigned short* pb = (cc & 1) ? Pb1 : Pb0;
    const unsigned short* pa = (cc & 1) ? Ab1 : Ab0;
    if (cc < 15) {
      patch_load(y_t, b, cc + 1, h0, w0, tid, pv);
      stage_A(wc, cc + 1, ocb, (cc & 1) ? Ab0 : Ab1, tid);
    }

#pragma unroll
    for (int kx = 0; kx < 3; ++kx) {
      bf16x8 bfr[4][2];
#pragma unroll
      for (int r = 0; r < 4; ++r)
#pragma unroll
        for (int ws = 0; ws < 2; ++ws) {
          int pidx = (pxg * 2 + r) * 34 + ws * 16 + l15 + kx;
          bfr[r][ws] = *reinterpret_cast<const bf16x8*>(
              pb + (pidx << 5) + ((gq ^ ((pidx >> 1) & 3)) << 3));
        }
      bf16x8 afr[3][4];
#pragma unroll
      for (int ky = 0; ky < 3; ++ky)
#pragma unroll
        for (int rt = 0; rt < 4; ++rt)
          afr[ky][rt] = *reinterpret_cast<const bf16x8*>(
              pa + (((ky * 3 + kx) * 4 + rt) << 9) + lane * 8);
#pragma unroll
      for (int ky = 0; ky < 3; ++ky)
#pragma unroll
        for (int ct = 0; ct < 4; ++ct) {
          int r = (ct >> 1) + ky, ws = ct & 1;
#pragma unroll
          for (int rt = 0; rt < 4; ++rt)
            acc[rt][ct] = MFMA16(afr[ky][rt], bfr[r][ws], acc[rt][ct]);
        }
    }

    if (cc < 15) patch_store((cc & 1) ? Pb0 : Pb1, tid, pv);
    __syncthreads();
  }

#pragma unroll
  for (int rt = 0; rt < 4; ++rt) {
    int oc0 = ocb * 64 + rt * 16 + gq * 4;
#pragma unroll
    for (int ct = 0; ct < 4; ++ct) {
      int hh = h0 + pxg * 2 + (ct >> 1), wp = w0 + ((ct & 1) << 4) + l15;
      long base = (((long)(b * 256 + oc0)) * 128 + hh) * 128 + wp;
#pragma unroll
      for (int j = 0; j < 4; ++j) out[base + (long)j * 16384] = acc[rt][ct][j];
    }
  }
}

// ================= BN stats / finalize / apply =================
__global__ void k_stats(const float* __restrict__ out, float* __restrict__ sums) {
  __shared__ float s1[256], s2[256];
  int c = blockIdx.x, tid = threadIdx.x;
  float a1 = 0.f, a2 = 0.f;
  for (int bb = 0; bb < 8; ++bb) {
    const float4* p = reinterpret_cast<const float4*>(out + ((long)(bb * 256 + c)) * 16384);
    for (int i = tid; i < 4096; i += 256) {
      float4 v = p[i];
      a1 += v.x + v.y + v.z + v.w;
      a2 += v.x * v.x + v.y * v.y + v.z * v.z + v.w * v.w;
    }
  }
  s1[tid] = a1; s2[tid] = a2;
  __syncthreads();
  for (int s = 128; s > 0; s >>= 1) {
    if (tid < s) { s1[tid] += s1[tid + s]; s2[tid] += s2[tid + s]; }
    __syncthreads();
  }
  if (tid == 0) { sums[c] = s1[0]; sums[256 + c] = s2[0]; }
}

__global__ void k_final(const float* __restrict__ sums, const float* __restrict__ gamma,
                        const float* __restrict__ beta, float* __restrict__ sc) {
  int c = threadIdx.x;
  float mean = sums[c] * (1.f / 131072.f);
  float var = sums[256 + c] * (1.f / 131072.f) - mean * mean;
  float s = gamma[c] * rsqrtf(var + 1e-5f);
  sc[c] = s;
  sc[256 + c] = beta[c] - mean * s;
}

__global__ void k_apply(float* __restrict__ out, const float* __restrict__ sc) {
  const long n4 = 33554432 / 4;
  for (long i4 = (long)blockIdx.x * 256 + threadIdx.x; i4 < n4; i4 += (long)gridDim.x * 256) {
    float4 v = reinterpret_cast<float4*>(out)[i4];
    int c = (int)((i4 >> 12) & 255);
    float s = sc[c], sh = sc[256 + c];
    v.x = fmaxf(v.x * s + sh, 0.f);
    v.y = fmaxf(v.y * s + sh, 0.f);
    v.z = fmaxf(v.z * s + sh, 0.f);
    v.w = fmaxf(v.w * s + sh, 0.f);
    reinterpret_cast<float4*>(out)[i4] = v;
  }
}

// ================= launch =================
extern "C" void kernel_launch(void* const* d_in, const int* in_sizes, int n_in,
                              void* d_out, int out_size, void* d_ws, size_t ws_size,
                              hipStream_t stream) {
  const float* x5 = (const float*)d_in[0];
  const float* d1 = (const float*)d_in[1];
  const float* d2 = (const float*)d_in[2];
  const float* kp = (const float*)d_in[3];
  const float* qp = (const float*)d_in[4];
  const float* vp = (const float*)d_in[5];
  const float* spw = (const float*)d_in[6];
  const float* inw = (const float*)d_in[7];
  const float* inb = (const float*)d_in[8];
  const float* opw = (const float*)d_in[9];
  const float* opb = (const float*)d_in[10];
  const float* pw = (const float*)d_in[11];
  const float* gamma = (const float*)d_in[12];
  const float* beta = (const float*)d_in[13];

  if (ws_size < (size_t)WSO_TOTAL) {
    fprintf(stderr, "kernel_launch: ws too small: %zu < %u\n", ws_size, WSO_TOTAL);
    return;
  }

  char* ws = (char*)d_ws;
  float* peT = (float*)(ws + WSO_PE);
  unsigned short* pwqs = (unsigned short*)(ws + WSO_PWQS);
  unsigned short* pwk = (unsigned short*)(ws + WSO_PWK);
  unsigned short* pwv = (unsigned short*)(ws + WSO_PWV);
  unsigned short* w_op = (unsigned short*)(ws + WSO_WOP);
  unsigned short* w_c = (unsigned short*)(ws + WSO_WC);
  unsigned short* tbh = (unsigned short*)(ws + WSO_TB);
  unsigned short* qh = (unsigned short*)(ws + WSO_QH);
  unsigned short* kh = (unsigned short*)(ws + WSO_KH);
  unsigned short* vt = (unsigned short*)(ws + WSO_VT);
  unsigned short* y_t = (unsigned short*)(ws + WSO_YT);
  float* sums = (float*)(ws + WSO_SUMS);
  float* sc = (float*)(ws + WSO_SC);

  hipFuncSetAttribute(reinterpret_cast<const void*>(k_conv),
                      hipFuncAttributeMaxDynamicSharedMemorySize, SMEM_CONV);
  hipFuncSetAttribute(reinterpret_cast<const void*>(k_proj),
                      hipFuncAttributeMaxDynamicSharedMemorySize, SMEM_PROJ);

  k_prep<<<5184, 256, 0, stream>>>(spw, opw, pw, peT, pwqs, w_op, w_c);
  k_fold<<<1536, 256, 0, stream>>>(qp, kp, vp, inw, inb, peT, pwqs, pwk, pwv, tbh);
  k_proj<<<3072, 512, SMEM_PROJ, stream>>>(x5, d1, d2, pwqs, pwk, pwv, tbh, qh, kh, vt, y_t);
  k_wattn<<<2048, 256, 0, stream>>>(qh, kh, vt, w_op, opb, y_t);
  k_conv<<<1024, 512, SMEM_CONV, stream>>>(y_t, w_c, (float*)d_out);
  k_stats<<<256, 256, 0, stream>>>((const float*)d_out, sums);
  k_final<<<1, 256, 0, stream>>>(sums, gamma, beta, sc);
  k_apply<<<2048, 256, 0, stream>>>((float*)d_out, sc);
}

// Round 11
// 741.127 us; speedup vs baseline: 1.0787x; 1.0687x over previous
//
#include <hip/hip_runtime.h>
#include <cstdio>
#include <cmath>

typedef __attribute__((ext_vector_type(8))) short bf16x8;
typedef __attribute__((ext_vector_type(4))) float f32x4;

#define MFMA16(a, b, c) __builtin_amdgcn_mfma_f32_16x16x32_bf16((a), (b), (c), 0, 0, 0)

// ---------------- workspace layout (byte offsets) ----------------
#define WSO_PE    0u                          // float[128*128]
#define WSO_PWQS  65536u                      // bf16 pack2 [kc8][og16][rt2][64][8]  (Wq@qp | sp)
#define WSO_PWK   (WSO_PWQS + 262144u)        // bf16 pack2 [kc16][og8][rt2][64][8]  Wk@kp
#define WSO_PWV   (WSO_PWK + 262144u)         // bf16 pack2 [kc8][og8][rt2][64][8]   Wv@vp
#define WSO_WOP   (WSO_PWV + 131072u)         // bf16 [256][256] row-major (k_wattn)
#define WSO_WC    (WSO_WOP + 131072u)         // bf16 conv fragment-packed
#define WSO_TB    (WSO_WC + 2359296u)         // bf16 [6][128][256] PE tables
#define WSO_QH    (WSO_TB + 786432u)          // bf16 [2048][8][64][32]
#define WSO_KH    (WSO_QH + 67108864u)        // bf16 [2048][8][64][32]
#define WSO_VT    (WSO_KH + 67108864u)        // bf16 [2048][8][32][64]
#define WSO_YT    (WSO_VT + 67108864u)        // bf16 [8][16cc][128][128][32c]
#define WSO_SUMS  (WSO_YT + 134217728u)       // float[512] (unused now)
#define WSO_SC    (WSO_SUMS + 2048u)          // float[512] (scale | shift)
#define WSO_PS    (WSO_SC + 2048u)            // float[256][256] partial sums
#define WSO_PSQ   (WSO_PS + 262144u)          // float[256][256] partial sumsq
#define WSO_TOTAL (WSO_PSQ + 262144u)

#define SMEM_CONV 152064
#define SMEM_PROJ 67584   // 128 px x 264 shorts x 2B

__device__ __forceinline__ unsigned short f2b(float x) {
  unsigned int u = __builtin_bit_cast(unsigned int, x);
  u += 0x7fffu + ((u >> 16) & 1u);
  return (unsigned short)(u >> 16);
}

__device__ __forceinline__ float b2f(unsigned short x) {
  return __builtin_bit_cast(float, ((unsigned int)x) << 16);
}

__device__ __forceinline__ bf16x8 rd8(const unsigned short* s, int row, int stride, int k) {
  return *reinterpret_cast<const bf16x8*>(s + row * stride + (k ^ ((row & 7) << 3)));
}

// pack2 for MFMA A operands: idx = (((kc*NOG + og)*2 + rt)*64 + lane)*8 + e
// oc = og*32 + rt*16 + (lane&15); ch = kc*32 + ((lane>>4)&3)*8 + e
__device__ __forceinline__ unsigned pack2(unsigned oc, unsigned ch, unsigned NOG) {
  unsigned kc = ch >> 5, og = oc >> 5, rt = (oc >> 4) & 1;
  unsigned l = (oc & 15) | (((ch >> 3) & 3) << 4), e = ch & 7;
  return (((kc * NOG + og) * 2 + rt) * 64 + l) * 8 + e;
}

// ================= prep: pe table + weight conversions =================
__global__ void k_prep(const float* __restrict__ spw, const float* __restrict__ opw,
                       const float* __restrict__ postw,
                       float* __restrict__ peT, unsigned short* __restrict__ pwqs,
                       unsigned short* __restrict__ wop, unsigned short* __restrict__ wc) {
  unsigned id = blockIdx.x * 256u + threadIdx.x;
  if (id < 16384u) {
    int p = id >> 7, j = id & 127;
    float div = expf(-9.210340371976184f * (float)(j & ~1) * (1.0f / 128.0f));
    float ang = (float)p * div;
    peT[id] = (j & 1) ? cosf(ang) : sinf(ang);
    return;
  }
  unsigned i = id - 16384u;
  if (i >= 1310720u) return;
  if (i < 65536u) {
    unsigned oc = i >> 8, ch = i & 255u;
    pwqs[pack2(oc + 256u, ch, 16u)] = f2b(spw[i]);
  } else if (i < 131072u) {
    wop[i - 65536u] = f2b(opw[i - 65536u]);
  } else {
    unsigned r = i - 131072u;
    unsigned e = r & 7u, l = (r >> 3) & 63u, rt = (r >> 9) & 3u;
    unsigned idx3 = r >> 11;
    unsigned tap = idx3 % 9u, q = idx3 / 9u;
    unsigned ocb = q & 3u, cc = q >> 2;
    unsigned oc = ocb * 64u + rt * 16u + (l & 15u);
    unsigned ic = cc * 32u + (l >> 4) * 8u + e;
    wc[r] = f2b(postw[(oc * 512u + ic) * 9u + tap]);
  }
}

// ================= fold: combined weights (pack2) + PE tables (bf16) =================
__global__ void k_fold(const float* __restrict__ qpw, const float* __restrict__ kpw,
                       const float* __restrict__ vpw, const float* __restrict__ inw,
                       const float* __restrict__ inb, const float* __restrict__ peT,
                       unsigned short* __restrict__ pwqs, unsigned short* __restrict__ pwk,
                       unsigned short* __restrict__ pwv, unsigned short* __restrict__ tbh) {
  __shared__ float wrow[256];
  const int tid = threadIdx.x, bid = blockIdx.x;
  if (bid < 768) {
    int m = bid >> 8;                 // 0 q, 1 k, 2 v
    int e2 = bid & 255;
    wrow[tid] = inw[(m * 256 + e2) * 256 + tid];
    __syncthreads();
    if (m == 1) {
      float a0 = 0.f, a1 = 0.f;
      for (int e = 0; e < 256; ++e) {
        float s = wrow[e];
        a0 = fmaf(s, kpw[e * 512 + tid], a0);
        a1 = fmaf(s, kpw[e * 512 + 256 + tid], a1);
      }
      pwk[pack2(e2, tid, 8u)] = f2b(a0);
      pwk[pack2(e2, tid + 256, 8u)] = f2b(a1);
    } else {
      const float* pw = (m == 0) ? qpw : vpw;
      float a0 = 0.f;
      for (int e = 0; e < 256; ++e) a0 = fmaf(wrow[e], pw[e * 256 + tid], a0);
      if (m == 0) pwqs[pack2(e2, tid, 16u)] = f2b(a0);
      else        pwv[pack2(e2, tid, 8u)] = f2b(a0);
    }
  } else {
    int r = bid - 768;
    int t = r >> 7, p = r & 127;      // t: 0 Aq,1 Bq,2 Ak,3 Bk,4 Av,5 Bv
    if (tid < 128) wrow[tid] = peT[p * 128 + tid];
    __syncthreads();
    int woff = (t >> 1) * 256, joff = (t & 1) * 128;
    float acc = (t & 1) ? 0.f : inb[woff + tid];
    const float* wr = inw + (size_t)(woff + tid) * 256 + joff;
    for (int j = 0; j < 128; ++j) acc = fmaf(wrow[j], wr[j], acc);
    tbh[t * 32768 + p * 256 + tid] = f2b(acc);
  }
}

// ================= shared GEMM (k_wattn): OUT[e][tok] += W[e][c] * X[tok][c] ===========
__device__ __forceinline__ void gemm4x4(f32x4 acc[4][4], const unsigned short* __restrict__ wA,
                                        int Kw, int kw0, const unsigned short* sB, int strideB,
                                        int nK, int wid, int lane) {
  const int rA = lane & 15;
  const int kq = (lane >> 4) << 3;
  for (int ks = 0; ks < nK; ks += 32) {
    bf16x8 a[4];
#pragma unroll
    for (int rt = 0; rt < 4; ++rt)
      a[rt] = *reinterpret_cast<const bf16x8*>(wA + (wid * 64 + rt * 16 + rA) * Kw + kw0 + ks + kq);
#pragma unroll
    for (int ct = 0; ct < 4; ++ct) {
      bf16x8 bb = rd8(sB, ct * 16 + rA, strideB, ks + kq);
#pragma unroll
      for (int rt = 0; rt < 4; ++rt) acc[rt][ct] = MFMA16(a[rt], bb, acc[rt][ct]);
    }
  }
}

// y_t layout: [b][cc=ch/32][h][w][ch%32]
__device__ __forceinline__ void epi_global(unsigned short* __restrict__ y_t, const f32x4 acc[4][4],
                                           const float* __restrict__ bias, int chOff,
                                           int b, int h0, int w0, int wid, int lane) {
#pragma unroll
  for (int rt = 0; rt < 4; ++rt) {
    int e0 = wid * 64 + rt * 16 + ((lane >> 4) << 2);
    float4 bs = bias ? *reinterpret_cast<const float4*>(bias + e0) : make_float4(0.f, 0.f, 0.f, 0.f);
    int ch = chOff + e0;
#pragma unroll
    for (int ct = 0; ct < 4; ++ct) {
      int tok = ct * 16 + (lane & 15);
      int r = tok >> 3, cpx = tok & 7;
      long gy = ((((long)(b * 16 + (ch >> 5)) * 128 + (h0 + r)) * 128 + (w0 + cpx)) << 5) + (ch & 31);
      ushort4 pk;
      pk.x = f2b(acc[rt][ct][0] + bs.x);
      pk.y = f2b(acc[rt][ct][1] + bs.y);
      pk.z = f2b(acc[rt][ct][2] + bs.z);
      pk.w = f2b(acc[rt][ct][3] + bs.w);
      *reinterpret_cast<ushort4*>(y_t + gy) = pk;
    }
  }
}

// ================= projections v6: full-row tiles (1h x 128w), perfect coalescing =====
// block = 512 thr / 8 waves; tile = one h-row x 128 w = 128 px; units bid%3:
//   0: qs (d1, q og0-7 + skip og8-15)   1: k (x5, 2 half-K phases)   2: v (d2)
// wave: tokG = wv&1 (64 px), ogPair = wv>>1; per wave 2 slots of 32oc -> acc[2][2][4]
// LDS [128 px][264]: col = (chL>>6)*64 + (((chL>>3)&7 ^ (px&7))<<3) + (chL&7)
__launch_bounds__(512, 4)
__global__ void k_proj(const float* __restrict__ x5, const float* __restrict__ d1,
                       const float* __restrict__ d2,
                       const unsigned short* __restrict__ pwqs, const unsigned short* __restrict__ pwk,
                       const unsigned short* __restrict__ pwv, const unsigned short* __restrict__ tbh,
                       unsigned short* __restrict__ qh, unsigned short* __restrict__ kh,
                       unsigned short* __restrict__ vt, unsigned short* __restrict__ y_t) {
  extern __shared__ unsigned short sB[];   // [128][264]
  const int tid = threadIdx.x, l = tid & 63, wv = tid >> 6;
  const int l15 = l & 15, gq = l >> 4;
  const int bid = blockIdx.x;
  const int unit = bid % 3, tile = bid / 3;
  const int h0 = tile & 127, b = tile >> 7;
  const int tokG = wv & 1, ogPair = wv >> 1;
  const int chsub = tid >> 4, pxg = (tid & 15) << 3;
  const int winRow = (b * 16 + (h0 >> 3)) << 4;

  // ---- staging: per kc (32 ch), thread loads 8 consecutive px of one ch ----
  auto ld2 = [&](const float* src, int Cin, int kc, float4& v0, float4& v1) {
    int ch = kc * 32 + chsub;
    const float* g = src + (((long)(b * Cin + ch)) << 14) + h0 * 128 + pxg;
    v0 = *reinterpret_cast<const float4*>(g);
    v1 = *reinterpret_cast<const float4*>(g + 4);
  };
  auto wr2 = [&](int kc, const float4& v0, const float4& v1) {
    int ch = kc * 32 + chsub, chL = ch & 255;
    int group = chL >> 6, gg = (chL >> 3) & 7, pos = chL & 7;
    const float* f0 = reinterpret_cast<const float*>(&v0);
    const float* f1 = reinterpret_cast<const float*>(&v1);
#pragma unroll
    for (int i = 0; i < 4; ++i) {
      int px = pxg + i;
      sB[px * 264 + (group << 6) + (((gg ^ (px & 7))) << 3) + pos] = f2b(f0[i]);
    }
#pragma unroll
    for (int i = 0; i < 4; ++i) {
      int px = pxg + 4 + i;
      sB[px * 264 + (group << 6) + (((gg ^ (px & 7))) << 3) + pos] = f2b(f1[i]);
    }
  };
  auto stageN = [&](const float* src, int Cin, int kc0, int n) {
    float4 a0, a1, b0, b1;
    ld2(src, Cin, kc0, a0, a1);
#pragma unroll 1
    for (int k = 0; k < n; ++k) {
      if (k + 1 < n) ld2(src, Cin, kc0 + k + 1, b0, b1);   // prefetch (T14)
      wr2(kc0 + k, a0, a1);
      a0 = b0; a1 = b1;
    }
  };

  const f32x4 vz = {0.f, 0.f, 0.f, 0.f};
  f32x4 acc[2][2][4];
  auto zacc = [&]() {
#pragma unroll
    for (int sl = 0; sl < 2; ++sl)
#pragma unroll
      for (int rt = 0; rt < 2; ++rt)
#pragma unroll
        for (int ct = 0; ct < 4; ++ct) acc[sl][rt][ct] = vz;
  };

  auto run = [&](const unsigned short* wf, int NOG, int ogBase, int kc0, int kcn) {
#pragma unroll 1
    for (int kc = kc0; kc < kc0 + kcn; ++kc) {
      const int kcL = kc & 7;
      const int chb = kcL * 32 + gq * 8;
      const int group = chb >> 6, gg = (chb >> 3) & 7;
      bf16x8 bb[4];
#pragma unroll
      for (int ct = 0; ct < 4; ++ct) {
        int px = tokG * 64 + ct * 16 + l15;
        bb[ct] = *reinterpret_cast<const bf16x8*>(
            &sB[px * 264 + (group << 6) + ((gg ^ (px & 7)) << 3)]);
      }
#pragma unroll
      for (int sl = 0; sl < 2; ++sl) {
        int og = ogBase + ogPair * 2 + sl;
        const unsigned short* pa = wf + (((((kc * NOG + og) << 7) + l)) << 3);
        bf16x8 a0 = *reinterpret_cast<const bf16x8*>(pa);
        bf16x8 a1 = *reinterpret_cast<const bf16x8*>(pa + 512);
#pragma unroll
        for (int ct = 0; ct < 4; ++ct) {
          acc[sl][0][ct] = MFMA16(a0, bb[ct], acc[sl][0][ct]);
          acc[sl][1][ct] = MFMA16(a1, bb[ct], acc[sl][1][ct]);
        }
      }
    }
  };

  auto epi_qk = [&](unsigned short* dstBase, const unsigned short* tA, const unsigned short* tB) {
#pragma unroll
    for (int sl = 0; sl < 2; ++sl) {
#pragma unroll
      for (int rt = 0; rt < 2; ++rt) {
        int oc = (ogPair * 2 + sl) * 32 + rt * 16 + gq * 4;
        int hd = oc >> 5, c31 = oc & 31;
        ushort4 av = *reinterpret_cast<const ushort4*>(&tA[h0 * 256 + oc]);
#pragma unroll
        for (int ct = 0; ct < 4; ++ct) {
          int px = tokG * 64 + ct * 16 + l15;
          ushort4 bv = *reinterpret_cast<const ushort4*>(&tB[px * 256 + oc]);
          int win = px >> 3, tokw = ((h0 & 7) << 3) | (px & 7);
          unsigned short* dst = dstBase + ((size_t)(winRow + win) << 14);
          ushort4 pk;
          pk.x = f2b(acc[sl][rt][ct][0] + b2f(av.x) + b2f(bv.x));
          pk.y = f2b(acc[sl][rt][ct][1] + b2f(av.y) + b2f(bv.y));
          pk.z = f2b(acc[sl][rt][ct][2] + b2f(av.z) + b2f(bv.z));
          pk.w = f2b(acc[sl][rt][ct][3] + b2f(av.w) + b2f(bv.w));
          *reinterpret_cast<ushort4*>(dst + (hd << 11) + (tokw << 5) + c31) = pk;
        }
      }
    }
  };

  if (unit == 0) {
    stageN(d1, 256, 0, 8);
    __syncthreads();
    zacc();
    run(pwqs, 16, 0, 0, 8);
    epi_qk(qh, tbh, tbh + 32768);
    zacc();
    run(pwqs, 16, 8, 0, 8);
    // skip -> y_t channels 256..511
#pragma unroll
    for (int sl = 0; sl < 2; ++sl)
#pragma unroll
      for (int rt = 0; rt < 2; ++rt) {
        int ch = (8 + ogPair * 2 + sl) * 32 + rt * 16 + gq * 4;
        int cc = ch >> 5;
#pragma unroll
        for (int ct = 0; ct < 4; ++ct) {
          int px = tokG * 64 + ct * 16 + l15;
          long gy = ((((long)(b * 16 + cc) * 128 + h0) * 128 + px) << 5) + (ch & 31);
          ushort4 pk;
          pk.x = f2b(acc[sl][rt][ct][0]);
          pk.y = f2b(acc[sl][rt][ct][1]);
          pk.z = f2b(acc[sl][rt][ct][2]);
          pk.w = f2b(acc[sl][rt][ct][3]);
          *reinterpret_cast<ushort4*>(y_t + gy) = pk;
        }
      }
  } else if (unit == 1) {
    stageN(x5, 512, 0, 8);
    __syncthreads();
    zacc();
    run(pwk, 8, 0, 0, 8);
    __syncthreads();
    stageN(x5, 512, 8, 8);
    __syncthreads();
    run(pwk, 8, 0, 8, 8);
    epi_qk(kh, tbh + 65536, tbh + 98304);
  } else {
    stageN(d2, 256, 0, 8);
    __syncthreads();
    zacc();
    run(pwv, 8, 0, 0, 8);
    // vT epilogue
    const unsigned short* tA = tbh + 131072;
    const unsigned short* tB = tbh + 163840;
#pragma unroll
    for (int sl = 0; sl < 2; ++sl)
#pragma unroll
      for (int rt = 0; rt < 2; ++rt) {
        int oc = (ogPair * 2 + sl) * 32 + rt * 16 + gq * 4;
        int hd = oc >> 5, chb = oc & 31;
        ushort4 av = *reinterpret_cast<const ushort4*>(&tA[h0 * 256 + oc]);
        const unsigned short* avp = reinterpret_cast<const unsigned short*>(&av);
#pragma unroll
        for (int ct = 0; ct < 4; ++ct) {
          int px = tokG * 64 + ct * 16 + l15;
          ushort4 bv = *reinterpret_cast<const ushort4*>(&tB[px * 256 + oc]);
          const unsigned short* bvp = reinterpret_cast<const unsigned short*>(&bv);
          int win = px >> 3, tokw = ((h0 & 7) << 3) | (px & 7);
          unsigned short* dst = vt + ((size_t)(winRow + win) << 14) + (hd << 11) + tokw;
#pragma unroll
          for (int j = 0; j < 4; ++j)
            dst[(chb + j) * 64] = f2b(acc[sl][rt][ct][j] + b2f(avp[j]) + b2f(bvp[j]));
        }
      }
  }
}

// ================= window attention + out-proj (unchanged) =================
__launch_bounds__(256, 3)
__global__ void k_wattn(const unsigned short* __restrict__ qh, const unsigned short* __restrict__ kh,
                        const unsigned short* __restrict__ vt, const unsigned short* __restrict__ wop,
                        const float* __restrict__ out_b, unsigned short* __restrict__ y_t) {
  __shared__ unsigned short Pb[4096];
  __shared__ unsigned short bufO[16384];
  const int tid = threadIdx.x, lane = tid & 63, wid = tid >> 6;
  const int gq = lane >> 4, l15 = lane & 15, kq = gq << 3;
  const int bid = blockIdx.x;
  const int win = ((bid & 7) << 8) | (bid >> 3);
  const int b = win >> 8, wh = (win >> 4) & 15, ww = win & 15;
  const int h0 = wh * 8, w0 = ww * 8;

  const unsigned short* qw = qh + ((size_t)win << 14);
  const unsigned short* kw = kh + ((size_t)win << 14);
  const unsigned short* vw = vt + ((size_t)win << 14);

  const f32x4 vz = {0.f, 0.f, 0.f, 0.f};
  const float scl = 0.17677669529663687f;
  f32x4 o0[8], o1[8];
#pragma unroll
  for (int h = 0; h < 8; ++h) { o0[h] = vz; o1[h] = vz; }

#pragma unroll
  for (int hd = 0; hd < 8; ++hd) {
    const unsigned short* qb = qw + (hd << 11);
    const unsigned short* kb = kw + (hd << 11);
    const unsigned short* vb = vw + (hd << 11);
    bf16x8 aq = *reinterpret_cast<const bf16x8*>(qb + ((wid * 16 + l15) << 5) + kq);
    f32x4 sv[4];
#pragma unroll
    for (int ct = 0; ct < 4; ++ct) {
      bf16x8 bk = *reinterpret_cast<const bf16x8*>(kb + ((ct * 16 + l15) << 5) + kq);
      sv[ct] = MFMA16(aq, bk, vz);
    }
    float pr[4][4];
#pragma unroll
    for (int j = 0; j < 4; ++j) {
      float mx = fmaxf(fmaxf(sv[0][j], sv[1][j]), fmaxf(sv[2][j], sv[3][j])) * scl;
#pragma unroll
      for (int m = 8; m >= 1; m >>= 1) mx = fmaxf(mx, __shfl_xor(mx, m));
      float sum = 0.f;
#pragma unroll
      for (int ct = 0; ct < 4; ++ct) {
        float p = __expf(sv[ct][j] * scl - mx);
        pr[ct][j] = p;
        sum += p;
      }
#pragma unroll
      for (int m = 8; m >= 1; m >>= 1) sum += __shfl_xor(sum, m);
      float inv = 1.f / sum;
#pragma unroll
      for (int ct = 0; ct < 4; ++ct) pr[ct][j] *= inv;
    }
#pragma unroll
    for (int ct = 0; ct < 4; ++ct)
#pragma unroll
      for (int j = 0; j < 4; ++j) {
        int q = wid * 16 + gq * 4 + j;
        int kt = ct * 16 + l15;
        Pb[q * 64 + (kt ^ ((q & 7) << 3))] = f2b(pr[ct][j]);
      }
#pragma unroll
    for (int ks = 0; ks < 64; ks += 32) {
      bf16x8 bp = rd8(Pb, wid * 16 + l15, 64, ks + kq);
      bf16x8 a0 = *reinterpret_cast<const bf16x8*>(vb + (l15 << 6) + ks + kq);
      bf16x8 a1 = *reinterpret_cast<const bf16x8*>(vb + ((16 + l15) << 6) + ks + kq);
      o0[hd] = MFMA16(a0, bp, o0[hd]);
      o1[hd] = MFMA16(a1, bp, o1[hd]);
    }
  }

  {
    int tok = wid * 16 + l15;
    int sw = (tok & 7) << 3;
#pragma unroll
    for (int hd = 0; hd < 8; ++hd)
#pragma unroll
      for (int rt = 0; rt < 2; ++rt) {
        f32x4 ov = rt ? o1[hd] : o0[hd];
        int ch0 = hd * 32 + rt * 16 + gq * 4;
        ushort4 pk;
        pk.x = f2b(ov[0]); pk.y = f2b(ov[1]); pk.z = f2b(ov[2]); pk.w = f2b(ov[3]);
        *reinterpret_cast<ushort4*>(&bufO[tok * 256 + (ch0 ^ sw)]) = pk;
      }
  }
  __syncthreads();

  f32x4 accA[4][4];
#pragma unroll
  for (int i = 0; i < 4; ++i)
#pragma unroll
    for (int j = 0; j < 4; ++j) accA[i][j] = vz;
  gemm4x4(accA, wop, 256, 0, bufO, 256, 256, wid, lane);
  epi_global(y_t, accA, out_b, 0, b, h0, w0, wid, lane);
}

// ================= conv 3x3 (512->256) implicit GEMM + fused BN stats =================
__device__ __forceinline__ void patch_load(const unsigned short* __restrict__ y_t,
                                           int b, int cc, int h0, int w0, int tid, uint4* pv) {
#pragma unroll
  for (int k = 0; k < 5; ++k) {
    int s = tid + (k << 9);
    uint4 v = make_uint4(0u, 0u, 0u, 0u);
    if (s < 2448) {
      int pr = (s * 482) >> 16;
      int rem = s - pr * 136;
      int pcpx = rem >> 2, g = rem & 3;
      int hh = h0 + pr - 1, wp = w0 + pcpx - 1;
      if ((unsigned)hh < 128u && (unsigned)wp < 128u)
        v = *reinterpret_cast<const uint4*>(
            y_t + ((((long)(b * 16 + cc) * 128 + hh) * 128 + wp) << 5) + (g << 3));
    }
    pv[k] = v;
  }
}

__device__ __forceinline__ void patch_store(unsigned short* buf, int tid, const uint4* pv) {
#pragma unroll
  for (int k = 0; k < 5; ++k) {
    int s = tid + (k << 9);
    if (s < 2448) {
      int pr = (s * 482) >> 16;
      int rem = s - pr * 136;
      int pcpx = rem >> 2, g = rem & 3;
      int pidx = pr * 34 + pcpx;
      *reinterpret_cast<uint4*>(buf + (pidx << 5) + ((g ^ ((pidx >> 1) & 3)) << 3)) = pv[k];
    }
  }
}

__device__ __forceinline__ void stage_A(const unsigned short* __restrict__ wA, int cc, int ocb,
                                        unsigned short* dstBase, int tid) {
  const unsigned short* src = wA + (size_t)(cc * 4 + ocb) * 18432 + tid * 8;
  unsigned short* dst = dstBase + tid * 8;
#pragma unroll
  for (int k = 0; k < 4; ++k) {
    __builtin_amdgcn_global_load_lds(
        (const __attribute__((address_space(1))) unsigned int*)(src + k * 4096),
        (__attribute__((address_space(3))) unsigned int*)(dst + k * 4096), 16, 0, 0);
  }
  if (tid < 256)
    __builtin_amdgcn_global_load_lds(
        (const __attribute__((address_space(1))) unsigned int*)(src + 16384),
        (__attribute__((address_space(3))) unsigned int*)(dst + 16384), 16, 0, 0);
}

__launch_bounds__(512, 2)
__global__ void k_conv(const unsigned short* __restrict__ y_t, const unsigned short* __restrict__ wc,
                       float* __restrict__ out, float* __restrict__ psum,
                       float* __restrict__ psq) {
  extern __shared__ unsigned short cs[];
  unsigned short* Pb0 = cs;
  unsigned short* Pb1 = cs + 19584;
  unsigned short* Ab0 = cs + 39168;
  unsigned short* Ab1 = cs + 57600;

  const int tid = threadIdx.x, lane = tid & 63, pxg = tid >> 6;
  const int gq = lane >> 4, l15 = lane & 15;
  const int bi = ((int)blockIdx.x & 7) * 128 + ((int)blockIdx.x >> 3);
  const int ocb = bi & 3, wb = (bi >> 2) & 3, hb = (bi >> 4) & 7, b = bi >> 7;
  const int h0 = hb * 16, w0 = wb * 32;

  const f32x4 vz = {0.f, 0.f, 0.f, 0.f};
  f32x4 acc[4][4];
#pragma unroll
  for (int rt = 0; rt < 4; ++rt)
#pragma unroll
    for (int ct = 0; ct < 4; ++ct) acc[rt][ct] = vz;

  uint4 pv[5];
  patch_load(y_t, b, 0, h0, w0, tid, pv);
  stage_A(wc, 0, ocb, Ab0, tid);
  patch_store(Pb0, tid, pv);
  __syncthreads();

#pragma unroll 1
  for (int cc = 0; cc < 16; ++cc) {
    const unsigned short* pb = (cc & 1) ? Pb1 : Pb0;
    const unsigned short* pa = (cc & 1) ? Ab1 : Ab0;
    if (cc < 15) {
      patch_load(y_t, b, cc + 1, h0, w0, tid, pv);
      stage_A(wc, cc + 1, ocb, (cc & 1) ? Ab0 : Ab1, tid);
    }

#pragma unroll
    for (int kx = 0; kx < 3; ++kx) {
      bf16x8 bfr[4][2];
#pragma unroll
      for (int r = 0; r < 4; ++r)
#pragma unroll
        for (int ws = 0; ws < 2; ++ws) {
          int pidx = (pxg * 2 + r) * 34 + ws * 16 + l15 + kx;
          bfr[r][ws] = *reinterpret_cast<const bf16x8*>(
              pb + (pidx << 5) + ((gq ^ ((pidx >> 1) & 3)) << 3));
        }
      bf16x8 afr[3][4];
#pragma unroll
      for (int ky = 0; ky < 3; ++ky)
#pragma unroll
        for (int rt = 0; rt < 4; ++rt)
          afr[ky][rt] = *reinterpret_cast<const bf16x8*>(
              pa + (((ky * 3 + kx) * 4 + rt) << 9) + lane * 8);
#pragma unroll
      for (int ky = 0; ky < 3; ++ky)
#pragma unroll
        for (int ct = 0; ct < 4; ++ct) {
          int r = (ct >> 1) + ky, ws = ct & 1;
#pragma unroll
          for (int rt = 0; rt < 4; ++rt)
            acc[rt][ct] = MFMA16(afr[ky][rt], bfr[r][ws], acc[rt][ct]);
        }
    }

    if (cc < 15) patch_store((cc & 1) ? Pb0 : Pb1, tid, pv);
    __syncthreads();
  }

#pragma unroll
  for (int rt = 0; rt < 4; ++rt) {
    int oc0 = ocb * 64 + rt * 16 + gq * 4;
#pragma unroll
    for (int ct = 0; ct < 4; ++ct) {
      int hh = h0 + pxg * 2 + (ct >> 1), wp = w0 + ((ct & 1) << 4) + l15;
      long base = (((long)(b * 256 + oc0)) * 128 + hh) * 128 + wp;
#pragma unroll
      for (int j = 0; j < 4; ++j) out[base + (long)j * 16384] = acc[rt][ct][j];
    }
  }

  // ---- fused BN partial stats: lane over ct, shuffle over l15, LDS over waves ----
  {
    float s1v[4][4], s2v[4][4];
#pragma unroll
    for (int rt = 0; rt < 4; ++rt)
#pragma unroll
      for (int j = 0; j < 4; ++j) {
        float a = 0.f, q = 0.f;
#pragma unroll
        for (int ct = 0; ct < 4; ++ct) { float y = acc[rt][ct][j]; a += y; q += y * y; }
        s1v[rt][j] = a; s2v[rt][j] = q;
      }
#pragma unroll
    for (int m = 8; m >= 1; m >>= 1)
#pragma unroll
      for (int rt = 0; rt < 4; ++rt)
#pragma unroll
        for (int j = 0; j < 4; ++j) {
          s1v[rt][j] += __shfl_xor(s1v[rt][j], m);
          s2v[rt][j] += __shfl_xor(s2v[rt][j], m);
        }
    __shared__ float redS[8][64], redQ[8][64];
    if (l15 == 0) {
#pragma unroll
      for (int rt = 0; rt < 4; ++rt)
#pragma unroll
        for (int j = 0; j < 4; ++j) {
          redS[pxg][rt * 16 + gq * 4 + j] = s1v[rt][j];
          redQ[pxg][rt * 16 + gq * 4 + j] = s2v[rt][j];
        }
    }
    __syncthreads();
    if (tid < 64) {
      float a = 0.f, q = 0.f;
#pragma unroll
      for (int w = 0; w < 8; ++w) { a += redS[w][tid]; q += redQ[w][tid]; }
      int pb2 = bi >> 2;
      psum[pb2 * 256 + ocb * 64 + tid] = a;
      psq[pb2 * 256 + ocb * 64 + tid] = q;
    }
  }
}

// ================= BN finalize / apply =================
__global__ void k_final(const float* __restrict__ psum, const float* __restrict__ psq,
                        const float* __restrict__ gamma, const float* __restrict__ beta,
                        float* __restrict__ sc) {
  int c = threadIdx.x;
  float s1 = 0.f, s2 = 0.f;
  for (int p = 0; p < 256; ++p) { s1 += psum[p * 256 + c]; s2 += psq[p * 256 + c]; }
  float mean = s1 * (1.f / 131072.f);
  float var = s2 * (1.f / 131072.f) - mean * mean;
  float s = gamma[c] * rsqrtf(var + 1e-5f);
  sc[c] = s;
  sc[256 + c] = beta[c] - mean * s;
}

__global__ void k_apply(float* __restrict__ out, const float* __restrict__ sc) {
  const long n4 = 33554432 / 4;
  for (long i4 = (long)blockIdx.x * 256 + threadIdx.x; i4 < n4; i4 += (long)gridDim.x * 256) {
    float4 v = reinterpret_cast<float4*>(out)[i4];
    int c = (int)((i4 >> 12) & 255);
    float s = sc[c], sh = sc[256 + c];
    v.x = fmaxf(v.x * s + sh, 0.f);
    v.y = fmaxf(v.y * s + sh, 0.f);
    v.z = fmaxf(v.z * s + sh, 0.f);
    v.w = fmaxf(v.w * s + sh, 0.f);
    reinterpret_cast<float4*>(out)[i4] = v;
  }
}

// ================= launch =================
extern "C" void kernel_launch(void* const* d_in, const int* in_sizes, int n_in,
                              void* d_out, int out_size, void* d_ws, size_t ws_size,
                              hipStream_t stream) {
  const float* x5 = (const float*)d_in[0];
  const float* d1 = (const float*)d_in[1];
  const float* d2 = (const float*)d_in[2];
  const float* kp = (const float*)d_in[3];
  const float* qp = (const float*)d_in[4];
  const float* vp = (const float*)d_in[5];
  const float* spw = (const float*)d_in[6];
  const float* inw = (const float*)d_in[7];
  const float* inb = (const float*)d_in[8];
  const float* opw = (const float*)d_in[9];
  const float* opb = (const float*)d_in[10];
  const float* pw = (const float*)d_in[11];
  const float* gamma = (const float*)d_in[12];
  const float* beta = (const float*)d_in[13];

  if (ws_size < (size_t)WSO_TOTAL) {
    fprintf(stderr, "kernel_launch: ws too small: %zu < %u\n", ws_size, WSO_TOTAL);
    return;
  }

  char* ws = (char*)d_ws;
  float* peT = (float*)(ws + WSO_PE);
  unsigned short* pwqs = (unsigned short*)(ws + WSO_PWQS);
  unsigned short* pwk = (unsigned short*)(ws + WSO_PWK);
  unsigned short* pwv = (unsigned short*)(ws + WSO_PWV);
  unsigned short* w_op = (unsigned short*)(ws + WSO_WOP);
  unsigned short* w_c = (unsigned short*)(ws + WSO_WC);
  unsigned short* tbh = (unsigned short*)(ws + WSO_TB);
  unsigned short* qh = (unsigned short*)(ws + WSO_QH);
  unsigned short* kh = (unsigned short*)(ws + WSO_KH);
  unsigned short* vt = (unsigned short*)(ws + WSO_VT);
  unsigned short* y_t = (unsigned short*)(ws + WSO_YT);
  float* sc = (float*)(ws + WSO_SC);
  float* psum = (float*)(ws + WSO_PS);
  float* psq = (float*)(ws + WSO_PSQ);

  hipFuncSetAttribute(reinterpret_cast<const void*>(k_conv),
                      hipFuncAttributeMaxDynamicSharedMemorySize, SMEM_CONV);
  hipFuncSetAttribute(reinterpret_cast<const void*>(k_proj),
                      hipFuncAttributeMaxDynamicSharedMemorySize, SMEM_PROJ);

  k_prep<<<5184, 256, 0, stream>>>(spw, opw, pw, peT, pwqs, w_op, w_c);
  k_fold<<<1536, 256, 0, stream>>>(qp, kp, vp, inw, inb, peT, pwqs, pwk, pwv, tbh);
  k_proj<<<3072, 512, SMEM_PROJ, stream>>>(x5, d1, d2, pwqs, pwk, pwv, tbh, qh, kh, vt, y_t);
  k_wattn<<<2048, 256, 0, stream>>>(qh, kh, vt, w_op, opb, y_t);
  k_conv<<<1024, 512, SMEM_CONV, stream>>>(y_t, w_c, (float*)d_out, psum, psq);
  k_final<<<1, 256, 0, stream>>>(psum, psq, gamma, beta, sc);
  k_apply<<<2048, 256, 0, stream>>>((float*)d_out, sc);
}

// Round 12
// 734.382 us; speedup vs baseline: 1.0886x; 1.0092x over previous
//
#include <hip/hip_runtime.h>
#include <cstdio>
#include <cmath>

typedef __attribute__((ext_vector_type(8))) short bf16x8;
typedef __attribute__((ext_vector_type(4))) float f32x4;

#define MFMA16(a, b, c) __builtin_amdgcn_mfma_f32_16x16x32_bf16((a), (b), (c), 0, 0, 0)

// ---------------- workspace layout (byte offsets) ----------------
#define WSO_PE    0u                          // float[128*128]
#define WSO_PWQS  65536u                      // bf16 pack2 [kc8][og16][rt2][64][8]  (Wq@qp | sp)
#define WSO_PWK   (WSO_PWQS + 262144u)        // bf16 pack2 [kc16][og8][rt2][64][8]  Wk@kp
#define WSO_PWV   (WSO_PWK + 262144u)         // bf16 pack2 [kc8][og8][rt2][64][8]   Wv@vp
#define WSO_WOP   (WSO_PWV + 131072u)         // bf16 [256][256] row-major (k_wattn)
#define WSO_WC    (WSO_WOP + 131072u)         // bf16 conv fragment-packed
#define WSO_TB    (WSO_WC + 2359296u)         // bf16 [6][128][256] PE tables
#define WSO_QH    (WSO_TB + 786432u)          // bf16 [2048][8][64][32]
#define WSO_KH    (WSO_QH + 67108864u)        // bf16 [2048][8][64][32]
#define WSO_VT    (WSO_KH + 67108864u)        // bf16 [2048][8][32][64]
#define WSO_YT    (WSO_VT + 67108864u)        // bf16 [8][16cc][128][128][32c]
#define WSO_SUMS  (WSO_YT + 134217728u)       // float[512] (unused now)
#define WSO_SC    (WSO_SUMS + 2048u)          // float[512] (scale | shift)
#define WSO_PS    (WSO_SC + 2048u)            // float[256][256] partial sums
#define WSO_PSQ   (WSO_PS + 262144u)          // float[256][256] partial sumsq
#define WSO_TOTAL (WSO_PSQ + 262144u)

#define SMEM_CONV 152064
#define SMEM_PROJ 67584   // 128 px x 264 shorts x 2B

__device__ __forceinline__ unsigned short f2b(float x) {
  unsigned int u = __builtin_bit_cast(unsigned int, x);
  u += 0x7fffu + ((u >> 16) & 1u);
  return (unsigned short)(u >> 16);
}

__device__ __forceinline__ float b2f(unsigned short x) {
  return __builtin_bit_cast(float, ((unsigned int)x) << 16);
}

__device__ __forceinline__ bf16x8 rd8(const unsigned short* s, int row, int stride, int k) {
  return *reinterpret_cast<const bf16x8*>(s + row * stride + (k ^ ((row & 7) << 3)));
}

// pack2 for MFMA A operands: idx = (((kc*NOG + og)*2 + rt)*64 + lane)*8 + e
// oc = og*32 + rt*16 + (lane&15); ch = kc*32 + ((lane>>4)&3)*8 + e
__device__ __forceinline__ unsigned pack2(unsigned oc, unsigned ch, unsigned NOG) {
  unsigned kc = ch >> 5, og = oc >> 5, rt = (oc >> 4) & 1;
  unsigned l = (oc & 15) | (((ch >> 3) & 3) << 4), e = ch & 7;
  return (((kc * NOG + og) * 2 + rt) * 64 + l) * 8 + e;
}

// ================= prep: pe table + weight conversions =================
__global__ void k_prep(const float* __restrict__ spw, const float* __restrict__ opw,
                       const float* __restrict__ postw,
                       float* __restrict__ peT, unsigned short* __restrict__ pwqs,
                       unsigned short* __restrict__ wop, unsigned short* __restrict__ wc) {
  unsigned id = blockIdx.x * 256u + threadIdx.x;
  if (id < 16384u) {
    int p = id >> 7, j = id & 127;
    float div = expf(-9.210340371976184f * (float)(j & ~1) * (1.0f / 128.0f));
    float ang = (float)p * div;
    peT[id] = (j & 1) ? cosf(ang) : sinf(ang);
    return;
  }
  unsigned i = id - 16384u;
  if (i >= 1310720u) return;
  if (i < 65536u) {
    unsigned oc = i >> 8, ch = i & 255u;
    pwqs[pack2(oc + 256u, ch, 16u)] = f2b(spw[i]);
  } else if (i < 131072u) {
    wop[i - 65536u] = f2b(opw[i - 65536u]);
  } else {
    unsigned r = i - 131072u;
    unsigned e = r & 7u, l = (r >> 3) & 63u, rt = (r >> 9) & 3u;
    unsigned idx3 = r >> 11;
    unsigned tap = idx3 % 9u, q = idx3 / 9u;
    unsigned ocb = q & 3u, cc = q >> 2;
    unsigned oc = ocb * 64u + rt * 16u + (l & 15u);
    unsigned ic = cc * 32u + (l >> 4) * 8u + e;
    wc[r] = f2b(postw[(oc * 512u + ic) * 9u + tap]);
  }
}

// ================= fold: combined weights (pack2) + PE tables (bf16) =================
__global__ void k_fold(const float* __restrict__ qpw, const float* __restrict__ kpw,
                       const float* __restrict__ vpw, const float* __restrict__ inw,
                       const float* __restrict__ inb, const float* __restrict__ peT,
                       unsigned short* __restrict__ pwqs, unsigned short* __restrict__ pwk,
                       unsigned short* __restrict__ pwv, unsigned short* __restrict__ tbh) {
  __shared__ float wrow[256];
  const int tid = threadIdx.x, bid = blockIdx.x;
  if (bid < 768) {
    int m = bid >> 8;                 // 0 q, 1 k, 2 v
    int e2 = bid & 255;
    wrow[tid] = inw[(m * 256 + e2) * 256 + tid];
    __syncthreads();
    if (m == 1) {
      float a0 = 0.f, a1 = 0.f;
      for (int e = 0; e < 256; ++e) {
        float s = wrow[e];
        a0 = fmaf(s, kpw[e * 512 + tid], a0);
        a1 = fmaf(s, kpw[e * 512 + 256 + tid], a1);
      }
      pwk[pack2(e2, tid, 8u)] = f2b(a0);
      pwk[pack2(e2, tid + 256, 8u)] = f2b(a1);
    } else {
      const float* pw = (m == 0) ? qpw : vpw;
      float a0 = 0.f;
      for (int e = 0; e < 256; ++e) a0 = fmaf(wrow[e], pw[e * 256 + tid], a0);
      if (m == 0) pwqs[pack2(e2, tid, 16u)] = f2b(a0);
      else        pwv[pack2(e2, tid, 8u)] = f2b(a0);
    }
  } else {
    int r = bid - 768;
    int t = r >> 7, p = r & 127;      // t: 0 Aq,1 Bq,2 Ak,3 Bk,4 Av,5 Bv
    if (tid < 128) wrow[tid] = peT[p * 128 + tid];
    __syncthreads();
    int woff = (t >> 1) * 256, joff = (t & 1) * 128;
    float acc = (t & 1) ? 0.f : inb[woff + tid];
    const float* wr = inw + (size_t)(woff + tid) * 256 + joff;
    for (int j = 0; j < 128; ++j) acc = fmaf(wrow[j], wr[j], acc);
    tbh[t * 32768 + p * 256 + tid] = f2b(acc);
  }
}

// ================= shared GEMM (k_wattn): OUT[e][tok] += W[e][c] * X[tok][c] ===========
__device__ __forceinline__ void gemm4x4(f32x4 acc[4][4], const unsigned short* __restrict__ wA,
                                        int Kw, int kw0, const unsigned short* sB, int strideB,
                                        int nK, int wid, int lane) {
  const int rA = lane & 15;
  const int kq = (lane >> 4) << 3;
  for (int ks = 0; ks < nK; ks += 32) {
    bf16x8 a[4];
#pragma unroll
    for (int rt = 0; rt < 4; ++rt)
      a[rt] = *reinterpret_cast<const bf16x8*>(wA + (wid * 64 + rt * 16 + rA) * Kw + kw0 + ks + kq);
#pragma unroll
    for (int ct = 0; ct < 4; ++ct) {
      bf16x8 bb = rd8(sB, ct * 16 + rA, strideB, ks + kq);
#pragma unroll
      for (int rt = 0; rt < 4; ++rt) acc[rt][ct] = MFMA16(a[rt], bb, acc[rt][ct]);
    }
  }
}

// y_t layout: [b][cc=ch/32][h][w][ch%32]
__device__ __forceinline__ void epi_global(unsigned short* __restrict__ y_t, const f32x4 acc[4][4],
                                           const float* __restrict__ bias, int chOff,
                                           int b, int h0, int w0, int wid, int lane) {
#pragma unroll
  for (int rt = 0; rt < 4; ++rt) {
    int e0 = wid * 64 + rt * 16 + ((lane >> 4) << 2);
    float4 bs = bias ? *reinterpret_cast<const float4*>(bias + e0) : make_float4(0.f, 0.f, 0.f, 0.f);
    int ch = chOff + e0;
#pragma unroll
    for (int ct = 0; ct < 4; ++ct) {
      int tok = ct * 16 + (lane & 15);
      int r = tok >> 3, cpx = tok & 7;
      long gy = ((((long)(b * 16 + (ch >> 5)) * 128 + (h0 + r)) * 128 + (w0 + cpx)) << 5) + (ch & 31);
      ushort4 pk;
      pk.x = f2b(acc[rt][ct][0] + bs.x);
      pk.y = f2b(acc[rt][ct][1] + bs.y);
      pk.z = f2b(acc[rt][ct][2] + bs.z);
      pk.w = f2b(acc[rt][ct][3] + bs.w);
      *reinterpret_cast<ushort4*>(y_t + gy) = pk;
    }
  }
}

// ================= projections v7: full-row tiles + shuffle-transpose staging ==========
// block = 512 thr / 8 waves; tile = one h-row x 128 w = 128 px; units bid%3:
//   0: qs (d1, q og0-7 + skip og8-15)   1: k (x5, 2 half-K phases)   2: v (d2)
// staging: lane (c3=l&7, p3=l>>3) loads 2x float4 (contiguous 128B/instr), 8x8 XOR-butterfly
// transpose across c3 -> lane holds 8 CHANNELS of one px -> single ds_write_b128.
// LDS [128 px][264 ch] plain (no swizzle): writes & reads provably conflict-free.
__launch_bounds__(512, 4)
__global__ void k_proj(const float* __restrict__ x5, const float* __restrict__ d1,
                       const float* __restrict__ d2,
                       const unsigned short* __restrict__ pwqs, const unsigned short* __restrict__ pwk,
                       const unsigned short* __restrict__ pwv, const unsigned short* __restrict__ tbh,
                       unsigned short* __restrict__ qh, unsigned short* __restrict__ kh,
                       unsigned short* __restrict__ vt, unsigned short* __restrict__ y_t) {
  extern __shared__ unsigned short sB[];   // [128][264]
  const int tid = threadIdx.x, l = tid & 63, wv = tid >> 6;
  const int l15 = l & 15, gq = l >> 4;
  const int bid = blockIdx.x;
  const int unit = bid % 3, tile = bid / 3;
  const int h0 = tile & 127, b = tile >> 7;
  const int tokG = wv & 1, ogPair = wv >> 1;
  const int winRow = (b * 16 + (h0 >> 3)) << 4;

  // staging lane map
  const int c3 = l & 7, p3 = l >> 3;
  const int hb = wv & 3, ph = wv >> 2;     // ch sub-block (8ch), px half (64px)

  const float* src; const unsigned short* wf; int Cin;
  if (unit == 0)      { src = d1; wf = pwqs; Cin = 256; }
  else if (unit == 1) { src = x5; wf = pwk;  Cin = 512; }
  else                { src = d2; wf = pwv;  Cin = 256; }

  auto ldT = [&](int kc, float4& v0, float4& v1) {
    int ch = kc * 32 + hb * 8 + c3;
    const float* g = src + (((long)(b * Cin + ch)) << 14) + h0 * 128 + ph * 64 + p3 * 4;
    v0 = *reinterpret_cast<const float4*>(g);
    v1 = *reinterpret_cast<const float4*>(g + 32);
  };
  auto wrT = [&](int kc, float4 v0, float4 v1) {
    float f0 = v0.x, f1 = v0.y, f2 = v0.z, f3 = v0.w;
    float f4 = v1.x, f5 = v1.y, f6 = v1.z, f7 = v1.w;
    float s, g;
    {  // stage m=1: pairs (0,1)(2,3)(4,5)(6,7)
      bool u = (c3 & 1) != 0;
      s = u ? f0 : f1; g = __shfl_xor(s, 1); f0 = u ? g : f0; f1 = u ? f1 : g;
      s = u ? f2 : f3; g = __shfl_xor(s, 1); f2 = u ? g : f2; f3 = u ? f3 : g;
      s = u ? f4 : f5; g = __shfl_xor(s, 1); f4 = u ? g : f4; f5 = u ? f5 : g;
      s = u ? f6 : f7; g = __shfl_xor(s, 1); f6 = u ? g : f6; f7 = u ? f7 : g;
    }
    {  // stage m=2: pairs (0,2)(1,3)(4,6)(5,7)
      bool u = (c3 & 2) != 0;
      s = u ? f0 : f2; g = __shfl_xor(s, 2); f0 = u ? g : f0; f2 = u ? f2 : g;
      s = u ? f1 : f3; g = __shfl_xor(s, 2); f1 = u ? g : f1; f3 = u ? f3 : g;
      s = u ? f4 : f6; g = __shfl_xor(s, 2); f4 = u ? g : f4; f6 = u ? f6 : g;
      s = u ? f5 : f7; g = __shfl_xor(s, 2); f5 = u ? g : f5; f7 = u ? f7 : g;
    }
    {  // stage m=4: pairs (0,4)(1,5)(2,6)(3,7)
      bool u = (c3 & 4) != 0;
      s = u ? f0 : f4; g = __shfl_xor(s, 4); f0 = u ? g : f0; f4 = u ? f4 : g;
      s = u ? f1 : f5; g = __shfl_xor(s, 4); f1 = u ? g : f1; f5 = u ? f5 : g;
      s = u ? f2 : f6; g = __shfl_xor(s, 4); f2 = u ? g : f2; f6 = u ? f6 : g;
      s = u ? f3 : f7; g = __shfl_xor(s, 4); f3 = u ? g : f3; f7 = u ? f7 : g;
    }
    // lane now holds ch hb*8+0..7 at px = ph*64 + ((c3&4)<<3) + p3*4 + (c3&3)
    bf16x8 pk;
    ((unsigned short*)&pk)[0] = f2b(f0);
    ((unsigned short*)&pk)[1] = f2b(f1);
    ((unsigned short*)&pk)[2] = f2b(f2);
    ((unsigned short*)&pk)[3] = f2b(f3);
    ((unsigned short*)&pk)[4] = f2b(f4);
    ((unsigned short*)&pk)[5] = f2b(f5);
    ((unsigned short*)&pk)[6] = f2b(f6);
    ((unsigned short*)&pk)[7] = f2b(f7);
    const int kcL = kc & 7;
    const int px = ph * 64 + ((c3 & 4) << 3) + p3 * 4 + (c3 & 3);
    *reinterpret_cast<bf16x8*>(&sB[px * 264 + kcL * 32 + hb * 8]) = pk;
  };
  auto stageN = [&](int kc0, int n) {
    float4 a0, a1, b0, b1;
    ldT(kc0, a0, a1);
#pragma unroll 1
    for (int k = 0; k < n; ++k) {
      if (k + 1 < n) ldT(kc0 + k + 1, b0, b1);   // prefetch (T14)
      wrT(kc0 + k, a0, a1);
      a0 = b0; a1 = b1;
    }
  };

  const f32x4 vz = {0.f, 0.f, 0.f, 0.f};
  f32x4 acc[2][2][4];
  auto zacc = [&]() {
#pragma unroll
    for (int sl = 0; sl < 2; ++sl)
#pragma unroll
      for (int rt = 0; rt < 2; ++rt)
#pragma unroll
        for (int ct = 0; ct < 4; ++ct) acc[sl][rt][ct] = vz;
  };

  auto run = [&](const unsigned short* wfp, int NOG, int ogBase, int kc0, int kcn) {
#pragma unroll 1
    for (int kc = kc0; kc < kc0 + kcn; ++kc) {
      const int kcL = kc & 7;
      bf16x8 bb[4];
#pragma unroll
      for (int ct = 0; ct < 4; ++ct) {
        int px = tokG * 64 + ct * 16 + l15;
        bb[ct] = *reinterpret_cast<const bf16x8*>(&sB[px * 264 + kcL * 32 + gq * 8]);
      }
#pragma unroll
      for (int sl = 0; sl < 2; ++sl) {
        int og = ogBase + ogPair * 2 + sl;
        const unsigned short* pa = wfp + (((((kc * NOG + og) << 7) + l)) << 3);
        bf16x8 a0 = *reinterpret_cast<const bf16x8*>(pa);
        bf16x8 a1 = *reinterpret_cast<const bf16x8*>(pa + 512);
#pragma unroll
        for (int ct = 0; ct < 4; ++ct) {
          acc[sl][0][ct] = MFMA16(a0, bb[ct], acc[sl][0][ct]);
          acc[sl][1][ct] = MFMA16(a1, bb[ct], acc[sl][1][ct]);
        }
      }
    }
  };

  auto epi_qk = [&](unsigned short* dstBase, const unsigned short* tA, const unsigned short* tB) {
#pragma unroll
    for (int sl = 0; sl < 2; ++sl) {
#pragma unroll
      for (int rt = 0; rt < 2; ++rt) {
        int oc = (ogPair * 2 + sl) * 32 + rt * 16 + gq * 4;
        int hd = oc >> 5, c31 = oc & 31;
        ushort4 av = *reinterpret_cast<const ushort4*>(&tA[h0 * 256 + oc]);
#pragma unroll
        for (int ct = 0; ct < 4; ++ct) {
          int px = tokG * 64 + ct * 16 + l15;
          ushort4 bv = *reinterpret_cast<const ushort4*>(&tB[px * 256 + oc]);
          int win = px >> 3, tokw = ((h0 & 7) << 3) | (px & 7);
          unsigned short* dst = dstBase + ((size_t)(winRow + win) << 14);
          ushort4 pk;
          pk.x = f2b(acc[sl][rt][ct][0] + b2f(av.x) + b2f(bv.x));
          pk.y = f2b(acc[sl][rt][ct][1] + b2f(av.y) + b2f(bv.y));
          pk.z = f2b(acc[sl][rt][ct][2] + b2f(av.z) + b2f(bv.z));
          pk.w = f2b(acc[sl][rt][ct][3] + b2f(av.w) + b2f(bv.w));
          *reinterpret_cast<ushort4*>(dst + (hd << 11) + (tokw << 5) + c31) = pk;
        }
      }
    }
  };

  if (unit == 0) {
    stageN(0, 8);
    __syncthreads();
    zacc();
    run(pwqs, 16, 0, 0, 8);
    epi_qk(qh, tbh, tbh + 32768);
    zacc();
    run(pwqs, 16, 8, 0, 8);
    // skip -> y_t channels 256..511
#pragma unroll
    for (int sl = 0; sl < 2; ++sl)
#pragma unroll
      for (int rt = 0; rt < 2; ++rt) {
        int ch = (8 + ogPair * 2 + sl) * 32 + rt * 16 + gq * 4;
        int cc = ch >> 5;
#pragma unroll
        for (int ct = 0; ct < 4; ++ct) {
          int px = tokG * 64 + ct * 16 + l15;
          long gy = ((((long)(b * 16 + cc) * 128 + h0) * 128 + px) << 5) + (ch & 31);
          ushort4 pk;
          pk.x = f2b(acc[sl][rt][ct][0]);
          pk.y = f2b(acc[sl][rt][ct][1]);
          pk.z = f2b(acc[sl][rt][ct][2]);
          pk.w = f2b(acc[sl][rt][ct][3]);
          *reinterpret_cast<ushort4*>(y_t + gy) = pk;
        }
      }
  } else if (unit == 1) {
    stageN(0, 8);
    __syncthreads();
    zacc();
    run(pwk, 8, 0, 0, 8);
    __syncthreads();                       // all waves done reading phase-1
    stageN(8, 8);
    __syncthreads();
    run(pwk, 8, 0, 8, 8);
    epi_qk(kh, tbh + 65536, tbh + 98304);
  } else {
    stageN(0, 8);
    __syncthreads();
    zacc();
    run(pwv, 8, 0, 0, 8);
    // vT epilogue
    const unsigned short* tA = tbh + 131072;
    const unsigned short* tB = tbh + 163840;
#pragma unroll
    for (int sl = 0; sl < 2; ++sl)
#pragma unroll
      for (int rt = 0; rt < 2; ++rt) {
        int oc = (ogPair * 2 + sl) * 32 + rt * 16 + gq * 4;
        int hd = oc >> 5, chb = oc & 31;
        ushort4 av = *reinterpret_cast<const ushort4*>(&tA[h0 * 256 + oc]);
        const unsigned short* avp = reinterpret_cast<const unsigned short*>(&av);
#pragma unroll
        for (int ct = 0; ct < 4; ++ct) {
          int px = tokG * 64 + ct * 16 + l15;
          ushort4 bv = *reinterpret_cast<const ushort4*>(&tB[px * 256 + oc]);
          const unsigned short* bvp = reinterpret_cast<const unsigned short*>(&bv);
          int win = px >> 3, tokw = ((h0 & 7) << 3) | (px & 7);
          unsigned short* dst = vt + ((size_t)(winRow + win) << 14) + (hd << 11) + tokw;
#pragma unroll
          for (int j = 0; j < 4; ++j)
            dst[(chb + j) * 64] = f2b(acc[sl][rt][ct][j] + b2f(avp[j]) + b2f(bvp[j]));
        }
      }
  }
}

// ================= window attention + out-proj (unchanged) =================
__launch_bounds__(256, 3)
__global__ void k_wattn(const unsigned short* __restrict__ qh, const unsigned short* __restrict__ kh,
                        const unsigned short* __restrict__ vt, const unsigned short* __restrict__ wop,
                        const float* __restrict__ out_b, unsigned short* __restrict__ y_t) {
  __shared__ unsigned short Pb[4096];
  __shared__ unsigned short bufO[16384];
  const int tid = threadIdx.x, lane = tid & 63, wid = tid >> 6;
  const int gq = lane >> 4, l15 = lane & 15, kq = gq << 3;
  const int bid = blockIdx.x;
  const int win = ((bid & 7) << 8) | (bid >> 3);
  const int b = win >> 8, wh = (win >> 4) & 15, ww = win & 15;
  const int h0 = wh * 8, w0 = ww * 8;

  const unsigned short* qw = qh + ((size_t)win << 14);
  const unsigned short* kw = kh + ((size_t)win << 14);
  const unsigned short* vw = vt + ((size_t)win << 14);

  const f32x4 vz = {0.f, 0.f, 0.f, 0.f};
  const float scl = 0.17677669529663687f;
  f32x4 o0[8], o1[8];
#pragma unroll
  for (int h = 0; h < 8; ++h) { o0[h] = vz; o1[h] = vz; }

#pragma unroll
  for (int hd = 0; hd < 8; ++hd) {
    const unsigned short* qb = qw + (hd << 11);
    const unsigned short* kb = kw + (hd << 11);
    const unsigned short* vb = vw + (hd << 11);
    bf16x8 aq = *reinterpret_cast<const bf16x8*>(qb + ((wid * 16 + l15) << 5) + kq);
    f32x4 sv[4];
#pragma unroll
    for (int ct = 0; ct < 4; ++ct) {
      bf16x8 bk = *reinterpret_cast<const bf16x8*>(kb + ((ct * 16 + l15) << 5) + kq);
      sv[ct] = MFMA16(aq, bk, vz);
    }
    float pr[4][4];
#pragma unroll
    for (int j = 0; j < 4; ++j) {
      float mx = fmaxf(fmaxf(sv[0][j], sv[1][j]), fmaxf(sv[2][j], sv[3][j])) * scl;
#pragma unroll
      for (int m = 8; m >= 1; m >>= 1) mx = fmaxf(mx, __shfl_xor(mx, m));
      float sum = 0.f;
#pragma unroll
      for (int ct = 0; ct < 4; ++ct) {
        float p = __expf(sv[ct][j] * scl - mx);
        pr[ct][j] = p;
        sum += p;
      }
#pragma unroll
      for (int m = 8; m >= 1; m >>= 1) sum += __shfl_xor(sum, m);
      float inv = 1.f / sum;
#pragma unroll
      for (int ct = 0; ct < 4; ++ct) pr[ct][j] *= inv;
    }
#pragma unroll
    for (int ct = 0; ct < 4; ++ct)
#pragma unroll
      for (int j = 0; j < 4; ++j) {
        int q = wid * 16 + gq * 4 + j;
        int kt = ct * 16 + l15;
        Pb[q * 64 + (kt ^ ((q & 7) << 3))] = f2b(pr[ct][j]);
      }
#pragma unroll
    for (int ks = 0; ks < 64; ks += 32) {
      bf16x8 bp = rd8(Pb, wid * 16 + l15, 64, ks + kq);
      bf16x8 a0 = *reinterpret_cast<const bf16x8*>(vb + (l15 << 6) + ks + kq);
      bf16x8 a1 = *reinterpret_cast<const bf16x8*>(vb + ((16 + l15) << 6) + ks + kq);
      o0[hd] = MFMA16(a0, bp, o0[hd]);
      o1[hd] = MFMA16(a1, bp, o1[hd]);
    }
  }

  {
    int tok = wid * 16 + l15;
    int sw = (tok & 7) << 3;
#pragma unroll
    for (int hd = 0; hd < 8; ++hd)
#pragma unroll
      for (int rt = 0; rt < 2; ++rt) {
        f32x4 ov = rt ? o1[hd] : o0[hd];
        int ch0 = hd * 32 + rt * 16 + gq * 4;
        ushort4 pk;
        pk.x = f2b(ov[0]); pk.y = f2b(ov[1]); pk.z = f2b(ov[2]); pk.w = f2b(ov[3]);
        *reinterpret_cast<ushort4*>(&bufO[tok * 256 + (ch0 ^ sw)]) = pk;
      }
  }
  __syncthreads();

  f32x4 accA[4][4];
#pragma unroll
  for (int i = 0; i < 4; ++i)
#pragma unroll
    for (int j = 0; j < 4; ++j) accA[i][j] = vz;
  gemm4x4(accA, wop, 256, 0, bufO, 256, 256, wid, lane);
  epi_global(y_t, accA, out_b, 0, b, h0, w0, wid, lane);
}

// ================= conv 3x3 (512->256) implicit GEMM + fused BN stats =================
__device__ __forceinline__ void patch_load(const unsigned short* __restrict__ y_t,
                                           int b, int cc, int h0, int w0, int tid, uint4* pv) {
#pragma unroll
  for (int k = 0; k < 5; ++k) {
    int s = tid + (k << 9);
    uint4 v = make_uint4(0u, 0u, 0u, 0u);
    if (s < 2448) {
      int pr = (s * 482) >> 16;
      int rem = s - pr * 136;
      int pcpx = rem >> 2, g = rem & 3;
      int hh = h0 + pr - 1, wp = w0 + pcpx - 1;
      if ((unsigned)hh < 128u && (unsigned)wp < 128u)
        v = *reinterpret_cast<const uint4*>(
            y_t + ((((long)(b * 16 + cc) * 128 + hh) * 128 + wp) << 5) + (g << 3));
    }
    pv[k] = v;
  }
}

__device__ __forceinline__ void patch_store(unsigned short* buf, int tid, const uint4* pv) {
#pragma unroll
  for (int k = 0; k < 5; ++k) {
    int s = tid + (k << 9);
    if (s < 2448) {
      int pr = (s * 482) >> 16;
      int rem = s - pr * 136;
      int pcpx = rem >> 2, g = rem & 3;
      int pidx = pr * 34 + pcpx;
      *reinterpret_cast<uint4*>(buf + (pidx << 5) + ((g ^ ((pidx >> 1) & 3)) << 3)) = pv[k];
    }
  }
}

__device__ __forceinline__ void stage_A(const unsigned short* __restrict__ wA, int cc, int ocb,
                                        unsigned short* dstBase, int tid) {
  const unsigned short* src = wA + (size_t)(cc * 4 + ocb) * 18432 + tid * 8;
  unsigned short* dst = dstBase + tid * 8;
#pragma unroll
  for (int k = 0; k < 4; ++k) {
    __builtin_amdgcn_global_load_lds(
        (const __attribute__((address_space(1))) unsigned int*)(src + k * 4096),
        (__attribute__((address_space(3))) unsigned int*)(dst + k * 4096), 16, 0, 0);
  }
  if (tid < 256)
    __builtin_amdgcn_global_load_lds(
        (const __attribute__((address_space(1))) unsigned int*)(src + 16384),
        (__attribute__((address_space(3))) unsigned int*)(dst + 16384), 16, 0, 0);
}

__launch_bounds__(512, 2)
__global__ void k_conv(const unsigned short* __restrict__ y_t, const unsigned short* __restrict__ wc,
                       float* __restrict__ out, float* __restrict__ psum,
                       float* __restrict__ psq) {
  extern __shared__ unsigned short cs[];
  unsigned short* Pb0 = cs;
  unsigned short* Pb1 = cs + 19584;
  unsigned short* Ab0 = cs + 39168;
  unsigned short* Ab1 = cs + 57600;

  const int tid = threadIdx.x, lane = tid & 63, pxg = tid >> 6;
  const int gq = lane >> 4, l15 = lane & 15;
  const int bi = ((int)blockIdx.x & 7) * 128 + ((int)blockIdx.x >> 3);
  const int ocb = bi & 3, wb = (bi >> 2) & 3, hb = (bi >> 4) & 7, b = bi >> 7;
  const int h0 = hb * 16, w0 = wb * 32;

  const f32x4 vz = {0.f, 0.f, 0.f, 0.f};
  f32x4 acc[4][4];
#pragma unroll
  for (int rt = 0; rt < 4; ++rt)
#pragma unroll
    for (int ct = 0; ct < 4; ++ct) acc[rt][ct] = vz;

  uint4 pv[5];
  patch_load(y_t, b, 0, h0, w0, tid, pv);
  stage_A(wc, 0, ocb, Ab0, tid);
  patch_store(Pb0, tid, pv);
  __syncthreads();

#pragma unroll 1
  for (int cc = 0; cc < 16; ++cc) {
    const unsigned short* pb = (cc & 1) ? Pb1 : Pb0;
    const unsigned short* pa = (cc & 1) ? Ab1 : Ab0;
    if (cc < 15) {
      patch_load(y_t, b, cc + 1, h0, w0, tid, pv);
      stage_A(wc, cc + 1, ocb, (cc & 1) ? Ab0 : Ab1, tid);
    }

#pragma unroll
    for (int kx = 0; kx < 3; ++kx) {
      bf16x8 bfr[4][2];
#pragma unroll
      for (int r = 0; r < 4; ++r)
#pragma unroll
        for (int ws = 0; ws < 2; ++ws) {
          int pidx = (pxg * 2 + r) * 34 + ws * 16 + l15 + kx;
          bfr[r][ws] = *reinterpret_cast<const bf16x8*>(
              pb + (pidx << 5) + ((gq ^ ((pidx >> 1) & 3)) << 3));
        }
      bf16x8 afr[3][4];
#pragma unroll
      for (int ky = 0; ky < 3; ++ky)
#pragma unroll
        for (int rt = 0; rt < 4; ++rt)
          afr[ky][rt] = *reinterpret_cast<const bf16x8*>(
              pa + (((ky * 3 + kx) * 4 + rt) << 9) + lane * 8);
#pragma unroll
      for (int ky = 0; ky < 3; ++ky)
#pragma unroll
        for (int ct = 0; ct < 4; ++ct) {
          int r = (ct >> 1) + ky, ws = ct & 1;
#pragma unroll
          for (int rt = 0; rt < 4; ++rt)
            acc[rt][ct] = MFMA16(afr[ky][rt], bfr[r][ws], acc[rt][ct]);
        }
    }

    if (cc < 15) patch_store((cc & 1) ? Pb0 : Pb1, tid, pv);
    __syncthreads();
  }

#pragma unroll
  for (int rt = 0; rt < 4; ++rt) {
    int oc0 = ocb * 64 + rt * 16 + gq * 4;
#pragma unroll
    for (int ct = 0; ct < 4; ++ct) {
      int hh = h0 + pxg * 2 + (ct >> 1), wp = w0 + ((ct & 1) << 4) + l15;
      long base = (((long)(b * 256 + oc0)) * 128 + hh) * 128 + wp;
#pragma unroll
      for (int j = 0; j < 4; ++j) out[base + (long)j * 16384] = acc[rt][ct][j];
    }
  }

  // ---- fused BN partial stats ----
  {
    float s1v[4][4], s2v[4][4];
#pragma unroll
    for (int rt = 0; rt < 4; ++rt)
#pragma unroll
      for (int j = 0; j < 4; ++j) {
        float a = 0.f, q = 0.f;
#pragma unroll
        for (int ct = 0; ct < 4; ++ct) { float y = acc[rt][ct][j]; a += y; q += y * y; }
        s1v[rt][j] = a; s2v[rt][j] = q;
      }
#pragma unroll
    for (int m = 8; m >= 1; m >>= 1)
#pragma unroll
      for (int rt = 0; rt < 4; ++rt)
#pragma unroll
        for (int j = 0; j < 4; ++j) {
          s1v[rt][j] += __shfl_xor(s1v[rt][j], m);
          s2v[rt][j] += __shfl_xor(s2v[rt][j], m);
        }
    __shared__ float redS[8][64], redQ[8][64];
    if (l15 == 0) {
#pragma unroll
      for (int rt = 0; rt < 4; ++rt)
#pragma unroll
        for (int j = 0; j < 4; ++j) {
          redS[pxg][rt * 16 + gq * 4 + j] = s1v[rt][j];
          redQ[pxg][rt * 16 + gq * 4 + j] = s2v[rt][j];
        }
    }
    __syncthreads();
    if (tid < 64) {
      float a = 0.f, q = 0.f;
#pragma unroll
      for (int w = 0; w < 8; ++w) { a += redS[w][tid]; q += redQ[w][tid]; }
      int pb2 = bi >> 2;
      psum[pb2 * 256 + ocb * 64 + tid] = a;
      psq[pb2 * 256 + ocb * 64 + tid] = q;
    }
  }
}

// ================= BN finalize / apply =================
__global__ void k_final(const float* __restrict__ psum, const float* __restrict__ psq,
                        const float* __restrict__ gamma, const float* __restrict__ beta,
                        float* __restrict__ sc) {
  int c = threadIdx.x;
  float s1 = 0.f, s2 = 0.f;
  for (int p = 0; p < 256; ++p) { s1 += psum[p * 256 + c]; s2 += psq[p * 256 + c]; }
  float mean = s1 * (1.f / 131072.f);
  float var = s2 * (1.f / 131072.f) - mean * mean;
  float s = gamma[c] * rsqrtf(var + 1e-5f);
  sc[c] = s;
  sc[256 + c] = beta[c] - mean * s;
}

__global__ void k_apply(float* __restrict__ out, const float* __restrict__ sc) {
  const long n4 = 33554432 / 4;
  for (long i4 = (long)blockIdx.x * 256 + threadIdx.x; i4 < n4; i4 += (long)gridDim.x * 256) {
    float4 v = reinterpret_cast<float4*>(out)[i4];
    int c = (int)((i4 >> 12) & 255);
    float s = sc[c], sh = sc[256 + c];
    v.x = fmaxf(v.x * s + sh, 0.f);
    v.y = fmaxf(v.y * s + sh, 0.f);
    v.z = fmaxf(v.z * s + sh, 0.f);
    v.w = fmaxf(v.w * s + sh, 0.f);
    reinterpret_cast<float4*>(out)[i4] = v;
  }
}

// ================= launch =================
extern "C" void kernel_launch(void* const* d_in, const int* in_sizes, int n_in,
                              void* d_out, int out_size, void* d_ws, size_t ws_size,
                              hipStream_t stream) {
  const float* x5 = (const float*)d_in[0];
  const float* d1 = (const float*)d_in[1];
  const float* d2 = (const float*)d_in[2];
  const float* kp = (const float*)d_in[3];
  const float* qp = (const float*)d_in[4];
  const float* vp = (const float*)d_in[5];
  const float* spw = (const float*)d_in[6];
  const float* inw = (const float*)d_in[7];
  const float* inb = (const float*)d_in[8];
  const float* opw = (const float*)d_in[9];
  const float* opb = (const float*)d_in[10];
  const float* pw = (const float*)d_in[11];
  const float* gamma = (const float*)d_in[12];
  const float* beta = (const float*)d_in[13];

  if (ws_size < (size_t)WSO_TOTAL) {
    fprintf(stderr, "kernel_launch: ws too small: %zu < %u\n", ws_size, WSO_TOTAL);
    return;
  }

  char* ws = (char*)d_ws;
  float* peT = (float*)(ws + WSO_PE);
  unsigned short* pwqs = (unsigned short*)(ws + WSO_PWQS);
  unsigned short* pwk = (unsigned short*)(ws + WSO_PWK);
  unsigned short* pwv = (unsigned short*)(ws + WSO_PWV);
  unsigned short* w_op = (unsigned short*)(ws + WSO_WOP);
  unsigned short* w_c = (unsigned short*)(ws + WSO_WC);
  unsigned short* tbh = (unsigned short*)(ws + WSO_TB);
  unsigned short* qh = (unsigned short*)(ws + WSO_QH);
  unsigned short* kh = (unsigned short*)(ws + WSO_KH);
  unsigned short* vt = (unsigned short*)(ws + WSO_VT);
  unsigned short* y_t = (unsigned short*)(ws + WSO_YT);
  float* sc = (float*)(ws + WSO_SC);
  float* psum = (float*)(ws + WSO_PS);
  float* psq = (float*)(ws + WSO_PSQ);

  hipFuncSetAttribute(reinterpret_cast<const void*>(k_conv),
                      hipFuncAttributeMaxDynamicSharedMemorySize, SMEM_CONV);
  hipFuncSetAttribute(reinterpret_cast<const void*>(k_proj),
                      hipFuncAttributeMaxDynamicSharedMemorySize, SMEM_PROJ);

  k_prep<<<5184, 256, 0, stream>>>(spw, opw, pw, peT, pwqs, w_op, w_c);
  k_fold<<<1536, 256, 0, stream>>>(qp, kp, vp, inw, inb, peT, pwqs, pwk, pwv, tbh);
  k_proj<<<3072, 512, SMEM_PROJ, stream>>>(x5, d1, d2, pwqs, pwk, pwv, tbh, qh, kh, vt, y_t);
  k_wattn<<<2048, 256, 0, stream>>>(qh, kh, vt, w_op, opb, y_t);
  k_conv<<<1024, 512, SMEM_CONV, stream>>>(y_t, w_c, (float*)d_out, psum, psq);
  k_final<<<1, 256, 0, stream>>>(psum, psq, gamma, beta, sc);
  k_apply<<<2048, 256, 0, stream>>>((float*)d_out, sc);
}